// Round 8
// baseline (436.452 us; speedup 1.0000x reference)
//
#include <hip/hip_runtime.h>
#include <hip/hip_bf16.h>

typedef __attribute__((ext_vector_type(8))) short short8;
typedef __attribute__((ext_vector_type(4))) float f32x4;

#define MFMA_B16(a, b, c) __builtin_amdgcn_mfma_f32_16x16x32_bf16((a), (b), (c), 0, 0, 0)

__device__ __forceinline__ float bf2f(unsigned short u) {
    union { unsigned int i; float f; } v; v.i = ((unsigned int)u) << 16; return v.f;
}
__device__ __forceinline__ unsigned short f2bf(float f) {
    union { float f; unsigned int i; } v; v.f = f;
    unsigned int r = v.i + 0x7fffu + ((v.i >> 16) & 1u);
    return (unsigned short)(r >> 16);
}
__device__ __forceinline__ float sigm(float x) {
    return __frcp_rn(1.0f + __expf(-x));
}
__device__ __forceinline__ float tanh_fast(float x) {
    return 1.0f - 2.0f * __frcp_rn(__expf(2.0f * x) + 1.0f);
}

// probe 256 shorts: count bf16-plausible exponent fields. fp32-as-shorts ~138,
// bf16 ~256. threshold 200 discriminates. Deterministic per call.
__device__ __forceinline__ bool probe_bf16(const unsigned short* p, int tid, int* s_cnt) {
    if (tid == 0) *s_cnt = 0;
    __syncthreads();
    unsigned short s = p[tid & 255];
    int e = (s >> 7) & 0xFF;
    if (tid < 256 && e >= 117 && e <= 137) atomicAdd(s_cnt, 1);
    __syncthreads();
    return *s_cnt >= 200;
}

// ---------------------------------------------------------------------------
// Convert the 22 weight/bias/h0 tensors (everything except x) to a bf16 arena.
// ---------------------------------------------------------------------------
struct WArgs {
    const void* src[22];
    int off[23];
};

__global__ __launch_bounds__(256)
void convert_w(WArgs a, unsigned short* __restrict__ arena,
               const unsigned short* __restrict__ probe)
{
    __shared__ int cnt;
    const bool bf = probe_bf16(probe, threadIdx.x, &cnt);
    const int total = a.off[22];
    for (int i = blockIdx.x * 256 + threadIdx.x; i < total; i += gridDim.x * 256) {
        int t = 0;
        while (t < 21 && i >= a.off[t + 1]) ++t;
        const int local = i - a.off[t];
        arena[i] = bf ? ((const unsigned short*)a.src[t])[local]
                      : f2bf(((const float*)a.src[t])[local]);
    }
}

// ---------------------------------------------------------------------------
// Layer 1: bidirectional GRU(64), relu candidate. 8 REAL batch rows per block
// (A-tile rows 8..15 are pad: clamped loads, guarded stores) -> 1024 blocks,
// 4 blocks/CU. h bf16 (K=64), x hi/lo bf16 (K=32), bias C-init, z/r chained.
// grid: (bchunk/8, 2), block 256.
// ---------------------------------------------------------------------------
__global__ __launch_bounds__(256, 1)
void gru1_kernel(const void* __restrict__ X, int cb, int bchunk,
                 const unsigned short* __restrict__ h0f,
                 const unsigned short* __restrict__ h0b,
                 const unsigned short* __restrict__ Wf, const unsigned short* __restrict__ Uf,
                 const unsigned short* __restrict__ bif, const unsigned short* __restrict__ brf,
                 const unsigned short* __restrict__ Wb, const unsigned short* __restrict__ Ub,
                 const unsigned short* __restrict__ bib, const unsigned short* __restrict__ brb,
                 unsigned short* __restrict__ seq)
{
    const int tid  = threadIdx.x;
    const int lane = tid & 63;
    const int wv   = tid >> 6;
    const int q    = lane >> 4;
    const int ln   = lane & 15;
    const int dir  = blockIdx.y;
    const int lb0  = blockIdx.x * 8;
    const int gb0  = cb + lb0;
    const int u    = wv * 16 + ln;

    const unsigned short* W  = dir ? Wb  : Wf;
    const unsigned short* U  = dir ? Ub  : Uf;
    const unsigned short* bi = dir ? bib : bif;
    const unsigned short* br = dir ? brb : brf;
    const unsigned short* h0 = dir ? h0b : h0f;

    __shared__ __align__(16) unsigned short Ah[2][16][80];   // h bf16 (+pad)
    __shared__ __align__(16) unsigned short Ax[2][16][40];   // x hi/lo (18 real), rest 0
    __shared__ int s_cnt;

    const bool xbf = probe_bf16((const unsigned short*)X, tid, &s_cnt);

    // zero both Ax buffers (pad rows + cols >=18 stay 0 forever)
    {
        unsigned short* p = &Ax[0][0][0];
        for (int i = tid; i < 2 * 16 * 40; i += 256) p[i] = 0;
    }
    __syncthreads();

    // load x(t=0): 8 rows x 9 feats -> hi/lo pairs
    {
        const int tx0 = dir ? 71 : 0;
        if (tid < 72) {
            int r = tid / 9, k = tid - 9 * r;
            size_t idx = ((size_t)(gb0 + r) * 72 + tx0) * 9 + k;
            unsigned short hv, lv;
            if (xbf) { hv = ((const unsigned short*)X)[idx]; lv = 0; }
            else { float v = ((const float*)X)[idx]; hv = f2bf(v); lv = f2bf(v - bf2f(hv)); }
            Ax[0][r][2 * k]     = hv;
            Ax[0][r][2 * k + 1] = lv;
        }
    }

    // B-fragments
    short8 bU[3][2];   // recurrent K=64
    short8 bW[3];      // x projection K=32 (18 real hi/lo)
#pragma unroll
    for (int g = 0; g < 3; ++g) {
        const int col = g * 64 + u;
#pragma unroll
        for (int ks = 0; ks < 2; ++ks) {
            short8 f;
#pragma unroll
            for (int j = 0; j < 8; ++j) {
                int kp = ks * 32 + q * 8 + j;
                f[j] = (short)U[(size_t)kp * 192 + col];
            }
            bU[g][ks] = f;
        }
        short8 fw;
#pragma unroll
        for (int j = 0; j < 8; ++j) {
            int kp = q * 8 + j;
            fw[j] = (kp < 18) ? (short)W[(size_t)(kp >> 1) * 192 + col] : (short)0;
        }
        bW[g] = fw;
    }

    const float bz  = bf2f(bi[u])       + bf2f(br[u]);
    const float brg = bf2f(bi[64 + u])  + bf2f(br[64 + u]);
    const float bih = bf2f(bi[128 + u]);
    const float brh = bf2f(br[128 + u]);
    const f32x4 Cz  = {bz,  bz,  bz,  bz};
    const f32x4 Cr  = {brg, brg, brg, brg};
    const f32x4 Chx = {bih, bih, bih, bih};
    const f32x4 Chr = {brh, brh, brh, brh};

    float hreg[4];
#pragma unroll
    for (int i = 0; i < 4; ++i) {
        int m = q * 4 + i;                      // 0..15; pad rows duplicate m&7
        float hv = bf2f(h0[(size_t)(gb0 + (m & 7)) * 64 + u]);
        hreg[i] = hv;
        Ah[0][m][u] = f2bf(hv);
    }
    __syncthreads();

    const int r2 = tid >> 3, c2 = tid & 7;           // flush map (tid<64): 8 rows x 8 int4
    const int r0x = tid / 9, k0x = tid - 9 * r0x;    // x prefetch map (tid<72)

    for (int t = 0; t < 72; ++t) {
        const int cur = t & 1, nb = cur ^ 1;

        // prefetch x(t+1) into registers
        unsigned short h0v = 0, l0v = 0;
        if (t < 71 && tid < 72) {
            const int tx = dir ? (70 - t) : (t + 1);
            size_t idx = ((size_t)(gb0 + r0x) * 72 + tx) * 9 + k0x;
            if (xbf) { h0v = ((const unsigned short*)X)[idx]; l0v = 0; }
            else { float v = ((const float*)X)[idx]; h0v = f2bf(v); l0v = f2bf(v - bf2f(h0v)); }
        }

        // flush h(t-1) (= Ah[cur]) to seq, coalesced
        if (t > 0 && tid < 64) {
            const int tw = dir ? (71 - (t - 1)) : (t - 1);
            int4 v = *(const int4*)&Ah[cur][r2][c2 * 8];
            *(int4*)(seq + ((size_t)tw * bchunk + lb0 + r2) * 128 + dir * 64 + c2 * 8) = v;
        }

        // MFMA phase: 9 per wave
        const unsigned short* ap = &Ah[cur][ln][0];
        short8 a0 = *(const short8*)(ap + q * 8);
        short8 a1 = *(const short8*)(ap + 32 + q * 8);
        short8 ax = *(const short8*)(&Ax[cur][ln][q * 8]);
        f32x4 az  = MFMA_B16(ax, bW[0], Cz);
        az        = MFMA_B16(a0, bU[0][0], az);
        az        = MFMA_B16(a1, bU[0][1], az);
        f32x4 ar  = MFMA_B16(ax, bW[1], Cr);
        ar        = MFMA_B16(a0, bU[1][0], ar);
        ar        = MFMA_B16(a1, bU[1][1], ar);
        f32x4 ahx = MFMA_B16(ax, bW[2], Chx);
        f32x4 ahr = MFMA_B16(a0, bU[2][0], Chr);
        ahr       = MFMA_B16(a1, bU[2][1], ahr);

        // gates + state update
#pragma unroll
        for (int i = 0; i < 4; ++i) {
            const int m = q * 4 + i;
            float z = sigm(az[i]);
            float r = sigm(ar[i]);
            float pre = ahx[i] + r * ahr[i];
            float hh = fmaxf(pre, 0.0f);
            float hn = hh + z * (hreg[i] - hh);
            hreg[i] = hn;
            Ah[nb][m][u] = f2bf(hn);
        }

        if (t < 71 && tid < 72) {
            Ax[nb][r0x][2 * k0x]     = h0v;
            Ax[nb][r0x][2 * k0x + 1] = l0v;
        }
        __syncthreads();
    }

    // final flush: h(71) lives in Ah[0]
    if (tid < 64) {
        const int tw = dir ? 0 : 71;
        int4 v = *(const int4*)&Ah[0][r2][c2 * 8];
        *(int4*)(seq + ((size_t)tw * bchunk + lb0 + r2) * 128 + dir * 64 + c2 * 8) = v;
    }
}

// ---------------------------------------------------------------------------
// Layer 2: bidirectional GRU(64), tanh. 8 real rows per block (pad clamped).
// h bf16 (K=64), fused input projection (K=128), bias C-init.
// Final states -> feat (B,128) fp32. grid (bchunk/8, 2), block 256.
// ---------------------------------------------------------------------------
__global__ __launch_bounds__(256, 1)
void gru2_kernel(const unsigned short* __restrict__ seq, int cb, int bchunk,
                 const unsigned short* __restrict__ W2f, const unsigned short* __restrict__ U2f,
                 const unsigned short* __restrict__ bi2f, const unsigned short* __restrict__ br2f,
                 const unsigned short* __restrict__ W2b, const unsigned short* __restrict__ U2b,
                 const unsigned short* __restrict__ bi2b, const unsigned short* __restrict__ br2b,
                 float* __restrict__ feat)
{
    const int tid  = threadIdx.x;
    const int lane = tid & 63;
    const int wv   = tid >> 6;
    const int q    = lane >> 4;
    const int ln   = lane & 15;
    const int dir  = blockIdx.y;
    const int lb0  = blockIdx.x * 8;
    const int gb0  = cb + lb0;
    const int u    = wv * 16 + ln;

    const unsigned short* W  = dir ? W2b  : W2f;
    const unsigned short* U  = dir ? U2b  : U2f;
    const unsigned short* bi = dir ? bi2b : bi2f;
    const unsigned short* br = dir ? br2b : br2f;

    __shared__ __align__(16) unsigned short Ah[2][16][80];   // h bf16
    __shared__ __align__(16) unsigned short As[2][16][144];  // seq slice K=128 (+16 pad)

    {
        unsigned short* p = &Ah[0][0][0];
        for (int i = tid; i < 2 * 16 * 80; i += 256) p[i] = 0;
    }

    const int r3 = tid >> 4, c3 = tid & 15;   // 16 rows x 16 int4; pad rows dup r3&7
    const int rs = lb0 + (r3 & 7);
    {
        const int tx0 = dir ? 71 : 0;
        size_t base = ((size_t)tx0 * bchunk + rs) * 128 + c3 * 8;
        *(int4*)&As[0][r3][c3 * 8] = *(const int4*)(seq + base);
    }

    short8 bU[3][2];   // recurrent K=64
    short8 bV[3][4];   // input projection K=128
#pragma unroll
    for (int g = 0; g < 3; ++g) {
        const int col = g * 64 + u;
#pragma unroll
        for (int ks = 0; ks < 2; ++ks) {
            short8 f;
#pragma unroll
            for (int j = 0; j < 8; ++j) {
                int kp = ks * 32 + q * 8 + j;
                f[j] = (short)U[(size_t)kp * 192 + col];
            }
            bU[g][ks] = f;
        }
#pragma unroll
        for (int ks = 0; ks < 4; ++ks) {
            short8 fv;
#pragma unroll
            for (int j = 0; j < 8; ++j) {
                int kp = ks * 32 + q * 8 + j;
                fv[j] = (short)W[(size_t)kp * 192 + col];
            }
            bV[g][ks] = fv;
        }
    }

    const float bz  = bf2f(bi[u])       + bf2f(br[u]);
    const float brg = bf2f(bi[64 + u])  + bf2f(br[64 + u]);
    const float bih = bf2f(bi[128 + u]);
    const float brh = bf2f(br[128 + u]);
    const f32x4 Cz  = {bz,  bz,  bz,  bz};
    const f32x4 Cr  = {brg, brg, brg, brg};
    const f32x4 Chx = {bih, bih, bih, bih};
    const f32x4 Chr = {brh, brh, brh, brh};

    float hreg[4];
#pragma unroll
    for (int i = 0; i < 4; ++i) hreg[i] = 0.0f;

    __syncthreads();

    for (int t = 0; t < 72; ++t) {
        const int cur = t & 1, nb = cur ^ 1;

        int4 g0;
        bool pf = (t < 71);
        if (pf) {
            const int tx = dir ? (70 - t) : (t + 1);
            size_t base = ((size_t)tx * bchunk + rs) * 128 + c3 * 8;
            g0 = *(const int4*)(seq + base);
        }

        const unsigned short* ap = &Ah[cur][ln][0];
        const unsigned short* sp = &As[cur][ln][0];
        short8 a0 = *(const short8*)(ap + q * 8);
        short8 a1 = *(const short8*)(ap + 32 + q * 8);
        short8 s0 = *(const short8*)(sp + q * 8);
        short8 s1 = *(const short8*)(sp + 32 + q * 8);
        short8 s2 = *(const short8*)(sp + 64 + q * 8);
        short8 s3 = *(const short8*)(sp + 96 + q * 8);

        f32x4 az  = MFMA_B16(s0, bV[0][0], Cz);
        az        = MFMA_B16(s1, bV[0][1], az);
        az        = MFMA_B16(s2, bV[0][2], az);
        az        = MFMA_B16(s3, bV[0][3], az);
        az        = MFMA_B16(a0, bU[0][0], az);
        az        = MFMA_B16(a1, bU[0][1], az);
        f32x4 ar  = MFMA_B16(s0, bV[1][0], Cr);
        ar        = MFMA_B16(s1, bV[1][1], ar);
        ar        = MFMA_B16(s2, bV[1][2], ar);
        ar        = MFMA_B16(s3, bV[1][3], ar);
        ar        = MFMA_B16(a0, bU[1][0], ar);
        ar        = MFMA_B16(a1, bU[1][1], ar);
        f32x4 ahx = MFMA_B16(s0, bV[2][0], Chx);
        ahx       = MFMA_B16(s1, bV[2][1], ahx);
        ahx       = MFMA_B16(s2, bV[2][2], ahx);
        ahx       = MFMA_B16(s3, bV[2][3], ahx);
        f32x4 ahr = MFMA_B16(a0, bU[2][0], Chr);
        ahr       = MFMA_B16(a1, bU[2][1], ahr);

#pragma unroll
        for (int i = 0; i < 4; ++i) {
            const int m = q * 4 + i;
            float z = sigm(az[i]);
            float r = sigm(ar[i]);
            float pre = ahx[i] + r * ahr[i];
            float hh = tanh_fast(pre);
            float hn = hh + z * (hreg[i] - hh);
            hreg[i] = hn;
            Ah[nb][m][u] = f2bf(hn);
        }

        if (pf) {
            *(int4*)&As[nb][r3][c3 * 8] = g0;
        }
        __syncthreads();
    }

#pragma unroll
    for (int i = 0; i < 4; ++i) {
        const int m = q * 4 + i;
        if (m < 8)
            feat[(size_t)(gb0 + m) * 128 + dir * 64 + u] = hreg[i];
    }
}

// ---------------------------------------------------------------------------
// Head: relu(feat @ dense_W + dense_b) @ out_W + out_b -> softmax -> fp32 out
// ---------------------------------------------------------------------------
__global__ __launch_bounds__(256, 1)
void head_kernel(const float* __restrict__ feat,
                 const unsigned short* __restrict__ dW, const unsigned short* __restrict__ db,
                 const unsigned short* __restrict__ oW, const unsigned short* __restrict__ ob,
                 float* __restrict__ out)
{
    const int tid = threadIdx.x;
    const int b0  = blockIdx.x * 16;

    __shared__ __align__(16) unsigned short Wl[128][136];
    __shared__ __align__(16) float fs[16][128];
    __shared__ __align__(16) float hs[16][136];
    __shared__ __align__(16) float ls[16][32];

    for (int i = tid; i < 2048; i += 256) {
        const int k = i >> 4;
        const int c = (i & 15) * 8;
        *(int4*)&Wl[k][c] = *(const int4*)(dW + (size_t)k * 128 + c);
    }
    {
        const float4* src = (const float4*)(feat + (size_t)b0 * 128);
        float4* dst = (float4*)&fs[0][0];
        for (int i = tid; i < 512; i += 256) dst[i] = src[i];
    }
    __syncthreads();

    {
        const int row = tid >> 4;
        const int j0  = (tid & 15) * 8;
        float acc[8];
#pragma unroll
        for (int jj = 0; jj < 8; ++jj) acc[jj] = bf2f(db[j0 + jj]);
        for (int k = 0; k < 128; ++k) {
            float f = fs[row][k];
            short8 w = *(const short8*)&Wl[k][j0];
#pragma unroll
            for (int jj = 0; jj < 8; ++jj)
                acc[jj] += f * bf2f((unsigned short)w[jj]);
        }
#pragma unroll
        for (int jj = 0; jj < 8; ++jj) hs[row][j0 + jj] = fmaxf(acc[jj], 0.0f);
    }
    __syncthreads();

    for (int e = tid; e < 16 * 24; e += 256) {
        const int row = e / 24, l = e - 24 * row;
        float acc = bf2f(ob[l]);
        for (int k = 0; k < 128; ++k)
            acc += hs[row][k] * bf2f(oW[(size_t)k * 24 + l]);
        ls[row][l] = acc;
    }
    __syncthreads();

    for (int e = tid; e < 16 * 24; e += 256) {
        const int row = e / 24, l = e - 24 * row;
        float mx = ls[row][0];
#pragma unroll
        for (int k = 1; k < 24; ++k) mx = fmaxf(mx, ls[row][k]);
        float s = 0.0f;
#pragma unroll
        for (int k = 0; k < 24; ++k) s += __expf(ls[row][k] - mx);
        float v = __expf(ls[row][l] - mx) * __frcp_rn(s);
        out[(size_t)(b0 + row) * 24 + l] = v;
    }
}

// ---------------------------------------------------------------------------
extern "C" void kernel_launch(void* const* d_in, const int* in_sizes, int n_in,
                              void* d_out, int out_size, void* d_ws, size_t ws_size,
                              hipStream_t stream) {
    (void)in_sizes; (void)n_in; (void)out_size;

    static const int wc[22] = {
        262144, 262144,
        1728, 12288, 192, 192,
        1728, 12288, 192, 192,
        24576, 12288, 192, 192,
        24576, 12288, 192, 192,
        16384, 128,
        3072, 24
    };

    WArgs a;
    int off = 0;
    for (int t = 0; t < 22; ++t) {
        a.src[t] = d_in[t + 1];
        a.off[t] = off;
        off += wc[t];
    }
    a.off[22] = off;

    const unsigned long long arena_bytes = 1294400ull;
    const unsigned long long feat_bytes  = 4096ull * 128ull * 4ull;
    const unsigned long long seq_full    = 72ull * 4096ull * 128ull * 2ull;
    const unsigned long long fixed       = arena_bytes + feat_bytes;

    int nc = 32;
    for (int c = 1; c <= 32; c *= 2) {
        if (fixed + seq_full / (unsigned long long)c <= (unsigned long long)ws_size) { nc = c; break; }
    }
    const int bchunk = 4096 / nc;

    unsigned short* arena = (unsigned short*)d_ws;
    float* feat           = (float*)((char*)d_ws + arena_bytes);
    unsigned short* seq   = (unsigned short*)((char*)d_ws + fixed);

    convert_w<<<64, 256, 0, stream>>>(a, arena, (const unsigned short*)d_in[0]);

    const unsigned short* h0f  = arena + a.off[0];
    const unsigned short* h0b  = arena + a.off[1];
    const unsigned short* d1fW = arena + a.off[2];
    const unsigned short* d1fU = arena + a.off[3];
    const unsigned short* d1fbi= arena + a.off[4];
    const unsigned short* d1fbr= arena + a.off[5];
    const unsigned short* d1bW = arena + a.off[6];
    const unsigned short* d1bU = arena + a.off[7];
    const unsigned short* d1bbi= arena + a.off[8];
    const unsigned short* d1bbr= arena + a.off[9];
    const unsigned short* d2fW = arena + a.off[10];
    const unsigned short* d2fU = arena + a.off[11];
    const unsigned short* d2fbi= arena + a.off[12];
    const unsigned short* d2fbr= arena + a.off[13];
    const unsigned short* d2bW = arena + a.off[14];
    const unsigned short* d2bU = arena + a.off[15];
    const unsigned short* d2bbi= arena + a.off[16];
    const unsigned short* d2bbr= arena + a.off[17];
    const unsigned short* dW   = arena + a.off[18];
    const unsigned short* db   = arena + a.off[19];
    const unsigned short* oW   = arena + a.off[20];
    const unsigned short* ob   = arena + a.off[21];

    for (int c = 0; c < nc; ++c) {
        const int cb = c * bchunk;
        gru1_kernel<<<dim3(bchunk / 8, 2), 256, 0, stream>>>(
            d_in[0], cb, bchunk,
            h0f, h0b, d1fW, d1fU, d1fbi, d1fbr, d1bW, d1bU, d1bbi, d1bbr, seq);
        gru2_kernel<<<dim3(bchunk / 8, 2), 256, 0, stream>>>(
            seq, cb, bchunk,
            d2fW, d2fU, d2fbi, d2fbr, d2bW, d2bU, d2bbi, d2bbr, feat);
    }
    head_kernel<<<256, 256, 0, stream>>>(
        feat, dW, db, oW, ob, (float*)d_out);
}

// Round 10
// 300.873 us; speedup vs baseline: 1.4506x; 1.4506x over previous
//
#include <hip/hip_runtime.h>
#include <hip/hip_bf16.h>

typedef __attribute__((ext_vector_type(8))) short short8;
typedef __attribute__((ext_vector_type(4))) float f32x4;

#define MFMA_B16(a, b, c) __builtin_amdgcn_mfma_f32_16x16x32_bf16((a), (b), (c), 0, 0, 0)

__device__ __forceinline__ float bf2f(unsigned short u) {
    union { unsigned int i; float f; } v; v.i = ((unsigned int)u) << 16; return v.f;
}
__device__ __forceinline__ unsigned short f2bf(float f) {
    union { float f; unsigned int i; } v; v.f = f;
    unsigned int r = v.i + 0x7fffu + ((v.i >> 16) & 1u);
    return (unsigned short)(r >> 16);
}
__device__ __forceinline__ float sigm(float x) {
    return __frcp_rn(1.0f + __expf(-x));
}
__device__ __forceinline__ float tanh_fast(float x) {
    return 1.0f - 2.0f * __frcp_rn(__expf(2.0f * x) + 1.0f);
}

// probe 256 shorts: bf16 vs fp32 discrimination (deterministic per call)
__device__ __forceinline__ bool probe_bf16(const unsigned short* p, int tid, int* s_cnt) {
    if (tid == 0) *s_cnt = 0;
    __syncthreads();
    unsigned short s = p[tid & 255];
    int e = (s >> 7) & 0xFF;
    if (tid < 256 && e >= 117 && e <= 137) atomicAdd(s_cnt, 1);
    __syncthreads();
    return *s_cnt >= 200;
}

// ---------------------------------------------------------------------------
struct WArgs {
    const void* src[22];
    int off[23];
};

__global__ __launch_bounds__(256)
void convert_w(WArgs a, unsigned short* __restrict__ arena,
               const unsigned short* __restrict__ probe)
{
    __shared__ int cnt;
    const bool bf = probe_bf16(probe, threadIdx.x, &cnt);
    const int total = a.off[22];
    for (int i = blockIdx.x * 256 + threadIdx.x; i < total; i += gridDim.x * 256) {
        int t = 0;
        while (t < 21 && i >= a.off[t + 1]) ++t;
        const int local = i - a.off[t];
        arena[i] = bf ? ((const unsigned short*)a.src[t])[local]
                      : f2bf(((const float*)a.src[t])[local]);
    }
}

// ---------------------------------------------------------------------------
// Layer 1: bidirectional GRU(64), relu candidate. 16 rows/block, h bf16 K=64,
// x hi/lo bf16 K=32 via LDS. Bias C-init, z/r chained. Ah stride 72 (2-way).
// grid: (bchunk/16, 2), block 256.
// ---------------------------------------------------------------------------
__global__ __launch_bounds__(256, 1)
void gru1_kernel(const void* __restrict__ X, int cb, int bchunk,
                 const unsigned short* __restrict__ h0f,
                 const unsigned short* __restrict__ h0b,
                 const unsigned short* __restrict__ Wf, const unsigned short* __restrict__ Uf,
                 const unsigned short* __restrict__ bif, const unsigned short* __restrict__ brf,
                 const unsigned short* __restrict__ Wb, const unsigned short* __restrict__ Ub,
                 const unsigned short* __restrict__ bib, const unsigned short* __restrict__ brb,
                 unsigned short* __restrict__ seq)
{
    const int tid  = threadIdx.x;
    const int lane = tid & 63;
    const int wv   = tid >> 6;
    const int q    = lane >> 4;
    const int ln   = lane & 15;
    const int dir  = blockIdx.y;
    const int lb0  = blockIdx.x * 16;
    const int gb0  = cb + lb0;
    const int u    = wv * 16 + ln;

    const unsigned short* W  = dir ? Wb  : Wf;
    const unsigned short* U  = dir ? Ub  : Uf;
    const unsigned short* bi = dir ? bib : bif;
    const unsigned short* br = dir ? brb : brf;
    const unsigned short* h0 = dir ? h0b : h0f;

    __shared__ __align__(16) unsigned short Ah[2][16][72];   // h bf16 (stride 72: 2-way)
    __shared__ __align__(16) unsigned short Ax[2][16][40];   // x hi/lo (18 real), rest 0
    __shared__ int s_cnt;

    const bool xbf = probe_bf16((const unsigned short*)X, tid, &s_cnt);

    {
        unsigned short* p = &Ax[0][0][0];
        for (int i = tid; i < 2 * 16 * 40; i += 256) p[i] = 0;
    }
    __syncthreads();

    {
        const int tx0 = dir ? 71 : 0;
        if (tid < 144) {
            int r = tid / 9, k = tid - 9 * r;
            size_t idx = ((size_t)(gb0 + r) * 72 + tx0) * 9 + k;
            unsigned short hv, lv;
            if (xbf) { hv = ((const unsigned short*)X)[idx]; lv = 0; }
            else { float v = ((const float*)X)[idx]; hv = f2bf(v); lv = f2bf(v - bf2f(hv)); }
            Ax[0][r][2 * k]     = hv;
            Ax[0][r][2 * k + 1] = lv;
        }
    }

    short8 bU[3][2];
    short8 bW[3];
#pragma unroll
    for (int g = 0; g < 3; ++g) {
        const int col = g * 64 + u;
#pragma unroll
        for (int ks = 0; ks < 2; ++ks) {
            short8 f;
#pragma unroll
            for (int j = 0; j < 8; ++j) {
                int kp = ks * 32 + q * 8 + j;
                f[j] = (short)U[(size_t)kp * 192 + col];
            }
            bU[g][ks] = f;
        }
        short8 fw;
#pragma unroll
        for (int j = 0; j < 8; ++j) {
            int kp = q * 8 + j;
            fw[j] = (kp < 18) ? (short)W[(size_t)(kp >> 1) * 192 + col] : (short)0;
        }
        bW[g] = fw;
    }

    const float bz  = bf2f(bi[u])       + bf2f(br[u]);
    const float brg = bf2f(bi[64 + u])  + bf2f(br[64 + u]);
    const float bih = bf2f(bi[128 + u]);
    const float brh = bf2f(br[128 + u]);
    const f32x4 Cz  = {bz,  bz,  bz,  bz};
    const f32x4 Cr  = {brg, brg, brg, brg};
    const f32x4 Chx = {bih, bih, bih, bih};
    const f32x4 Chr = {brh, brh, brh, brh};

    float hreg[4];
#pragma unroll
    for (int i = 0; i < 4; ++i) {
        int m = q * 4 + i;
        float hv = bf2f(h0[(size_t)(gb0 + m) * 64 + u]);
        hreg[i] = hv;
        Ah[0][m][u] = f2bf(hv);
    }
    __syncthreads();

    const int r2 = tid >> 3, c2 = tid & 7;
    const int r0x = tid / 9, k0x = tid - 9 * r0x;

    for (int t = 0; t < 72; ++t) {
        const int cur = t & 1, nb = cur ^ 1;

        unsigned short h0v = 0, l0v = 0;
        if (t < 71 && tid < 144) {
            const int tx = dir ? (70 - t) : (t + 1);
            size_t idx = ((size_t)(gb0 + r0x) * 72 + tx) * 9 + k0x;
            if (xbf) { h0v = ((const unsigned short*)X)[idx]; l0v = 0; }
            else { float v = ((const float*)X)[idx]; h0v = f2bf(v); l0v = f2bf(v - bf2f(h0v)); }
        }

        if (t > 0 && tid < 128) {
            const int tw = dir ? (71 - (t - 1)) : (t - 1);
            int4 v = *(const int4*)&Ah[cur][r2][c2 * 8];
            *(int4*)(seq + ((size_t)tw * bchunk + lb0 + r2) * 128 + dir * 64 + c2 * 8) = v;
        }

        const unsigned short* ap = &Ah[cur][ln][0];
        short8 a0 = *(const short8*)(ap + q * 8);
        short8 a1 = *(const short8*)(ap + 32 + q * 8);
        short8 ax = *(const short8*)(&Ax[cur][ln][q * 8]);
        f32x4 az  = MFMA_B16(ax, bW[0], Cz);
        az        = MFMA_B16(a0, bU[0][0], az);
        az        = MFMA_B16(a1, bU[0][1], az);
        f32x4 ar  = MFMA_B16(ax, bW[1], Cr);
        ar        = MFMA_B16(a0, bU[1][0], ar);
        ar        = MFMA_B16(a1, bU[1][1], ar);
        f32x4 ahx = MFMA_B16(ax, bW[2], Chx);
        f32x4 ahr = MFMA_B16(a0, bU[2][0], Chr);
        ahr       = MFMA_B16(a1, bU[2][1], ahr);

#pragma unroll
        for (int i = 0; i < 4; ++i) {
            const int m = q * 4 + i;
            float z = sigm(az[i]);
            float r = sigm(ar[i]);
            float pre = ahx[i] + r * ahr[i];
            float hh = fmaxf(pre, 0.0f);
            float hn = hh + z * (hreg[i] - hh);
            hreg[i] = hn;
            Ah[nb][m][u] = f2bf(hn);
        }

        if (t < 71 && tid < 144) {
            Ax[nb][r0x][2 * k0x]     = h0v;
            Ax[nb][r0x][2 * k0x + 1] = l0v;
        }
        __syncthreads();
    }

    // final flush: h(71) lives in Ah[0]; 16 rows x 8 int4 -> 128 threads
    if (tid < 128) {
        const int tw = dir ? 0 : 71;
        int4 v = *(const int4*)&Ah[0][r2][c2 * 8];
        *(int4*)(seq + ((size_t)tw * bchunk + lb0 + r2) * 128 + dir * 64 + c2 * 8) = v;
    }
}

// ---------------------------------------------------------------------------
// Layer 2: bidirectional GRU(64), tanh. NO As LDS: each lane loads its seq
// A-fragments directly from global one step ahead; the 12 input-projection
// MFMAs run pre-barrier (partials P for t+1), post-barrier only 6 recurrent
// MFMAs + gates. Ah stride 72. grid (bchunk/16, 2), block 256.
// ---------------------------------------------------------------------------
__global__ __launch_bounds__(256, 1)
void gru2_kernel(const unsigned short* __restrict__ seq, int cb, int bchunk,
                 const unsigned short* __restrict__ W2f, const unsigned short* __restrict__ U2f,
                 const unsigned short* __restrict__ bi2f, const unsigned short* __restrict__ br2f,
                 const unsigned short* __restrict__ W2b, const unsigned short* __restrict__ U2b,
                 const unsigned short* __restrict__ bi2b, const unsigned short* __restrict__ br2b,
                 float* __restrict__ feat)
{
    const int tid  = threadIdx.x;
    const int lane = tid & 63;
    const int wv   = tid >> 6;
    const int q    = lane >> 4;
    const int ln   = lane & 15;
    const int dir  = blockIdx.y;
    const int lb0  = blockIdx.x * 16;
    const int gb0  = cb + lb0;
    const int u    = wv * 16 + ln;

    const unsigned short* W  = dir ? W2b  : W2f;
    const unsigned short* U  = dir ? U2b  : U2f;
    const unsigned short* bi = dir ? bi2b : bi2f;
    const unsigned short* br = dir ? br2b : br2f;

    __shared__ __align__(16) unsigned short Ah[2][16][72];

    {
        unsigned short* p = &Ah[0][0][0];
        for (int i = tid; i < 16 * 72; i += 256) p[i] = 0;
    }

    // per-lane seq A-frag pointer: row = lb0+ln, chunk base q*8; step stride +-bchunk*128
    const long long tstride = (long long)bchunk * 128 * (dir ? -1 : 1);
    const unsigned short* sptr0 = seq + ((size_t)(lb0 + ln)) * 128 + q * 8
                                + (dir ? 71ll * bchunk * 128 : 0);

    short8 bU[3][2];
    short8 bV[3][4];
#pragma unroll
    for (int g = 0; g < 3; ++g) {
        const int col = g * 64 + u;
#pragma unroll
        for (int ks = 0; ks < 2; ++ks) {
            short8 f;
#pragma unroll
            for (int j = 0; j < 8; ++j) {
                int kp = ks * 32 + q * 8 + j;
                f[j] = (short)U[(size_t)kp * 192 + col];
            }
            bU[g][ks] = f;
        }
#pragma unroll
        for (int ks = 0; ks < 4; ++ks) {
            short8 fv;
#pragma unroll
            for (int j = 0; j < 8; ++j) {
                int kp = ks * 32 + q * 8 + j;
                fv[j] = (short)W[(size_t)kp * 192 + col];
            }
            bV[g][ks] = fv;
        }
    }

    const float bz  = bf2f(bi[u])       + bf2f(br[u]);
    const float brg = bf2f(bi[64 + u])  + bf2f(br[64 + u]);
    const float bih = bf2f(bi[128 + u]);
    const float brh = bf2f(br[128 + u]);
    const f32x4 Cz  = {bz,  bz,  bz,  bz};
    const f32x4 Cr  = {brg, brg, brg, brg};
    const f32x4 Chx = {bih, bih, bih, bih};
    const f32x4 Chr = {brh, brh, brh, brh};

    float hreg[4];
#pragma unroll
    for (int i = 0; i < 4; ++i) hreg[i] = 0.0f;

    // prologue: load s(0) and compute partials P(0)
    f32x4 P0, P1, P2;
    {
        const unsigned short* sp = sptr0;
        short8 s0 = *(const short8*)(sp);
        short8 s1 = *(const short8*)(sp + 32);
        short8 s2 = *(const short8*)(sp + 64);
        short8 s3 = *(const short8*)(sp + 96);
        P0 = MFMA_B16(s0, bV[0][0], Cz);
        P0 = MFMA_B16(s1, bV[0][1], P0);
        P0 = MFMA_B16(s2, bV[0][2], P0);
        P0 = MFMA_B16(s3, bV[0][3], P0);
        P1 = MFMA_B16(s0, bV[1][0], Cr);
        P1 = MFMA_B16(s1, bV[1][1], P1);
        P1 = MFMA_B16(s2, bV[1][2], P1);
        P1 = MFMA_B16(s3, bV[1][3], P1);
        P2 = MFMA_B16(s0, bV[2][0], Chx);
        P2 = MFMA_B16(s1, bV[2][1], P2);
        P2 = MFMA_B16(s2, bV[2][2], P2);
        P2 = MFMA_B16(s3, bV[2][3], P2);
    }
    __syncthreads();

    for (int t = 0; t < 72; ++t) {
        const int cur = t & 1, nb = cur ^ 1;

        // issue global loads for s(t+1) A-frags (consumed pre-barrier below)
        short8 n0, n1, n2, n3;
        const bool pf = (t < 71);
        if (pf) {
            const unsigned short* sp = sptr0 + (long long)(t + 1) * tstride;
            n0 = *(const short8*)(sp);
            n1 = *(const short8*)(sp + 32);
            n2 = *(const short8*)(sp + 64);
            n3 = *(const short8*)(sp + 96);
        }

        // post-barrier: finish gates with recurrent terms
        const unsigned short* ap = &Ah[cur][ln][0];
        short8 a0 = *(const short8*)(ap + q * 8);
        short8 a1 = *(const short8*)(ap + 32 + q * 8);
        f32x4 az  = MFMA_B16(a0, bU[0][0], P0);
        az        = MFMA_B16(a1, bU[0][1], az);
        f32x4 ar  = MFMA_B16(a0, bU[1][0], P1);
        ar        = MFMA_B16(a1, bU[1][1], ar);
        f32x4 ahr = MFMA_B16(a0, bU[2][0], Chr);
        ahr       = MFMA_B16(a1, bU[2][1], ahr);
        f32x4 ahx = P2;

#pragma unroll
        for (int i = 0; i < 4; ++i) {
            const int m = q * 4 + i;
            float z = sigm(az[i]);
            float r = sigm(ar[i]);
            float pre = ahx[i] + r * ahr[i];
            float hh = tanh_fast(pre);
            float hn = hh + z * (hreg[i] - hh);
            hreg[i] = hn;
            Ah[nb][m][u] = f2bf(hn);
        }

        // pre-barrier: input-projection partials for t+1 (MFMA pipe, overlaps gates)
        if (pf) {
            P0 = MFMA_B16(n0, bV[0][0], Cz);
            P0 = MFMA_B16(n1, bV[0][1], P0);
            P0 = MFMA_B16(n2, bV[0][2], P0);
            P0 = MFMA_B16(n3, bV[0][3], P0);
            P1 = MFMA_B16(n0, bV[1][0], Cr);
            P1 = MFMA_B16(n1, bV[1][1], P1);
            P1 = MFMA_B16(n2, bV[1][2], P1);
            P1 = MFMA_B16(n3, bV[1][3], P1);
            P2 = MFMA_B16(n0, bV[2][0], Chx);
            P2 = MFMA_B16(n1, bV[2][1], P2);
            P2 = MFMA_B16(n2, bV[2][2], P2);
            P2 = MFMA_B16(n3, bV[2][3], P2);
        }
        __syncthreads();
    }

#pragma unroll
    for (int i = 0; i < 4; ++i) {
        const int m = q * 4 + i;
        feat[(size_t)(gb0 + m) * 128 + dir * 64 + u] = hreg[i];
    }
}

// ---------------------------------------------------------------------------
__global__ __launch_bounds__(256, 1)
void head_kernel(const float* __restrict__ feat,
                 const unsigned short* __restrict__ dW, const unsigned short* __restrict__ db,
                 const unsigned short* __restrict__ oW, const unsigned short* __restrict__ ob,
                 float* __restrict__ out)
{
    const int tid = threadIdx.x;
    const int b0  = blockIdx.x * 16;

    __shared__ __align__(16) unsigned short Wl[128][136];
    __shared__ __align__(16) float fs[16][128];
    __shared__ __align__(16) float hs[16][136];
    __shared__ __align__(16) float ls[16][32];

    for (int i = tid; i < 2048; i += 256) {
        const int k = i >> 4;
        const int c = (i & 15) * 8;
        *(int4*)&Wl[k][c] = *(const int4*)(dW + (size_t)k * 128 + c);
    }
    {
        const float4* src = (const float4*)(feat + (size_t)b0 * 128);
        float4* dst = (float4*)&fs[0][0];
        for (int i = tid; i < 512; i += 256) dst[i] = src[i];
    }
    __syncthreads();

    {
        const int row = tid >> 4;
        const int j0  = (tid & 15) * 8;
        float acc[8];
#pragma unroll
        for (int jj = 0; jj < 8; ++jj) acc[jj] = bf2f(db[j0 + jj]);
        for (int k = 0; k < 128; ++k) {
            float f = fs[row][k];
            short8 w = *(const short8*)&Wl[k][j0];
#pragma unroll
            for (int jj = 0; jj < 8; ++jj)
                acc[jj] += f * bf2f((unsigned short)w[jj]);
        }
#pragma unroll
        for (int jj = 0; jj < 8; ++jj) hs[row][j0 + jj] = fmaxf(acc[jj], 0.0f);
    }
    __syncthreads();

    for (int e = tid; e < 16 * 24; e += 256) {
        const int row = e / 24, l = e - 24 * row;
        float acc = bf2f(ob[l]);
        for (int k = 0; k < 128; ++k)
            acc += hs[row][k] * bf2f(oW[(size_t)k * 24 + l]);
        ls[row][l] = acc;
    }
    __syncthreads();

    for (int e = tid; e < 16 * 24; e += 256) {
        const int row = e / 24, l = e - 24 * row;
        float mx = ls[row][0];
#pragma unroll
        for (int k = 1; k < 24; ++k) mx = fmaxf(mx, ls[row][k]);
        float s = 0.0f;
#pragma unroll
        for (int k = 0; k < 24; ++k) s += __expf(ls[row][k] - mx);
        float v = __expf(ls[row][l] - mx) * __frcp_rn(s);
        out[(size_t)(b0 + row) * 24 + l] = v;
    }
}

// ---------------------------------------------------------------------------
extern "C" void kernel_launch(void* const* d_in, const int* in_sizes, int n_in,
                              void* d_out, int out_size, void* d_ws, size_t ws_size,
                              hipStream_t stream) {
    (void)in_sizes; (void)n_in; (void)out_size;

    static const int wc[22] = {
        262144, 262144,
        1728, 12288, 192, 192,
        1728, 12288, 192, 192,
        24576, 12288, 192, 192,
        24576, 12288, 192, 192,
        16384, 128,
        3072, 24
    };

    WArgs a;
    int off = 0;
    for (int t = 0; t < 22; ++t) {
        a.src[t] = d_in[t + 1];
        a.off[t] = off;
        off += wc[t];
    }
    a.off[22] = off;

    const unsigned long long arena_bytes = 1294400ull;
    const unsigned long long feat_bytes  = 4096ull * 128ull * 4ull;
    const unsigned long long seq_full    = 72ull * 4096ull * 128ull * 2ull;
    const unsigned long long fixed       = arena_bytes + feat_bytes;

    int nc = 32;
    for (int c = 1; c <= 32; c *= 2) {
        if (fixed + seq_full / (unsigned long long)c <= (unsigned long long)ws_size) { nc = c; break; }
    }
    const int bchunk = 4096 / nc;

    unsigned short* arena = (unsigned short*)d_ws;
    float* feat           = (float*)((char*)d_ws + arena_bytes);
    unsigned short* seq   = (unsigned short*)((char*)d_ws + fixed);

    convert_w<<<256, 256, 0, stream>>>(a, arena, (const unsigned short*)d_in[0]);

    const unsigned short* h0f  = arena + a.off[0];
    const unsigned short* h0b  = arena + a.off[1];
    const unsigned short* d1fW = arena + a.off[2];
    const unsigned short* d1fU = arena + a.off[3];
    const unsigned short* d1fbi= arena + a.off[4];
    const unsigned short* d1fbr= arena + a.off[5];
    const unsigned short* d1bW = arena + a.off[6];
    const unsigned short* d1bU = arena + a.off[7];
    const unsigned short* d1bbi= arena + a.off[8];
    const unsigned short* d1bbr= arena + a.off[9];
    const unsigned short* d2fW = arena + a.off[10];
    const unsigned short* d2fU = arena + a.off[11];
    const unsigned short* d2fbi= arena + a.off[12];
    const unsigned short* d2fbr= arena + a.off[13];
    const unsigned short* d2bW = arena + a.off[14];
    const unsigned short* d2bU = arena + a.off[15];
    const unsigned short* d2bbi= arena + a.off[16];
    const unsigned short* d2bbr= arena + a.off[17];
    const unsigned short* dW   = arena + a.off[18];
    const unsigned short* db   = arena + a.off[19];
    const unsigned short* oW   = arena + a.off[20];
    const unsigned short* ob   = arena + a.off[21];

    for (int c = 0; c < nc; ++c) {
        const int cb = c * bchunk;
        gru1_kernel<<<dim3(bchunk / 16, 2), 256, 0, stream>>>(
            d_in[0], cb, bchunk,
            h0f, h0b, d1fW, d1fU, d1fbi, d1fbr, d1bW, d1bU, d1bbi, d1bbr, seq);
        gru2_kernel<<<dim3(bchunk / 16, 2), 256, 0, stream>>>(
            seq, cb, bchunk,
            d2fW, d2fU, d2fbi, d2fbr, d2bW, d2bU, d2bbi, d2bbr, feat);
    }
    head_kernel<<<256, 256, 0, stream>>>(
        feat, dW, db, oW, ob, (float*)d_out);
}

// Round 11
// 264.298 us; speedup vs baseline: 1.6514x; 1.1384x over previous
//
#include <hip/hip_runtime.h>
#include <hip/hip_bf16.h>

typedef __attribute__((ext_vector_type(8))) short short8;
typedef __attribute__((ext_vector_type(4))) float f32x4;

#define MFMA_B16(a, b, c) __builtin_amdgcn_mfma_f32_16x16x32_bf16((a), (b), (c), 0, 0, 0)

__device__ __forceinline__ float bf2f(unsigned short u) {
    union { unsigned int i; float f; } v; v.i = ((unsigned int)u) << 16; return v.f;
}
__device__ __forceinline__ unsigned short f2bf(float f) {
    union { float f; unsigned int i; } v; v.f = f;
    unsigned int r = v.i + 0x7fffu + ((v.i >> 16) & 1u);
    return (unsigned short)(r >> 16);
}
// fast HW transcendentals: v_rcp_f32 / v_exp_f32 (1 inst each, ~1 ulp).
// __frcp_rn was lowering to the full correctly-rounded div sequence (~12 inst)
// -> was ~30% of gate VALU. log2(e) folded into exp2 argument.
__device__ __forceinline__ float rcp_f(float x) { return __builtin_amdgcn_rcpf(x); }
__device__ __forceinline__ float sigm(float x) {
    return rcp_f(1.0f + __builtin_amdgcn_exp2f(-1.44269504f * x));
}
__device__ __forceinline__ float tanh_fast(float x) {
    return 1.0f - 2.0f * rcp_f(__builtin_amdgcn_exp2f(2.88539008f * x) + 1.0f);
}

// probe 256 shorts: bf16 vs fp32 discrimination (deterministic per call)
__device__ __forceinline__ bool probe_bf16(const unsigned short* p, int tid, int* s_cnt) {
    if (tid == 0) *s_cnt = 0;
    __syncthreads();
    unsigned short s = p[tid & 255];
    int e = (s >> 7) & 0xFF;
    if (tid < 256 && e >= 117 && e <= 137) atomicAdd(s_cnt, 1);
    __syncthreads();
    return *s_cnt >= 200;
}

// ---------------------------------------------------------------------------
struct WArgs {
    const void* src[22];
    int off[23];
};

__global__ __launch_bounds__(256)
void convert_w(WArgs a, unsigned short* __restrict__ arena,
               const unsigned short* __restrict__ probe)
{
    __shared__ int cnt;
    const bool bf = probe_bf16(probe, threadIdx.x, &cnt);
    const int total = a.off[22];
    for (int i = blockIdx.x * 256 + threadIdx.x; i < total; i += gridDim.x * 256) {
        int t = 0;
        while (t < 21 && i >= a.off[t + 1]) ++t;
        const int local = i - a.off[t];
        arena[i] = bf ? ((const unsigned short*)a.src[t])[local]
                      : f2bf(((const float*)a.src[t])[local]);
    }
}

// ---------------------------------------------------------------------------
// Layer 1: bidirectional GRU(64), relu candidate. 16 rows/block, h bf16 K=64,
// x hi/lo bf16 K=32 via LDS. Bias C-init, z/r chained. Ah stride 72 (2-way).
// grid: (bchunk/16, 2), block 256.
// ---------------------------------------------------------------------------
__global__ __launch_bounds__(256, 1)
void gru1_kernel(const void* __restrict__ X, int cb, int bchunk,
                 const unsigned short* __restrict__ h0f,
                 const unsigned short* __restrict__ h0b,
                 const unsigned short* __restrict__ Wf, const unsigned short* __restrict__ Uf,
                 const unsigned short* __restrict__ bif, const unsigned short* __restrict__ brf,
                 const unsigned short* __restrict__ Wb, const unsigned short* __restrict__ Ub,
                 const unsigned short* __restrict__ bib, const unsigned short* __restrict__ brb,
                 unsigned short* __restrict__ seq)
{
    const int tid  = threadIdx.x;
    const int lane = tid & 63;
    const int wv   = tid >> 6;
    const int q    = lane >> 4;
    const int ln   = lane & 15;
    const int dir  = blockIdx.y;
    const int lb0  = blockIdx.x * 16;
    const int gb0  = cb + lb0;
    const int u    = wv * 16 + ln;

    const unsigned short* W  = dir ? Wb  : Wf;
    const unsigned short* U  = dir ? Ub  : Uf;
    const unsigned short* bi = dir ? bib : bif;
    const unsigned short* br = dir ? brb : brf;
    const unsigned short* h0 = dir ? h0b : h0f;

    __shared__ __align__(16) unsigned short Ah[2][16][72];   // h bf16 (stride 72: 2-way)
    __shared__ __align__(16) unsigned short Ax[2][16][40];   // x hi/lo (18 real), rest 0
    __shared__ int s_cnt;

    const bool xbf = probe_bf16((const unsigned short*)X, tid, &s_cnt);

    {
        unsigned short* p = &Ax[0][0][0];
        for (int i = tid; i < 2 * 16 * 40; i += 256) p[i] = 0;
    }
    __syncthreads();

    {
        const int tx0 = dir ? 71 : 0;
        if (tid < 144) {
            int r = tid / 9, k = tid - 9 * r;
            size_t idx = ((size_t)(gb0 + r) * 72 + tx0) * 9 + k;
            unsigned short hv, lv;
            if (xbf) { hv = ((const unsigned short*)X)[idx]; lv = 0; }
            else { float v = ((const float*)X)[idx]; hv = f2bf(v); lv = f2bf(v - bf2f(hv)); }
            Ax[0][r][2 * k]     = hv;
            Ax[0][r][2 * k + 1] = lv;
        }
    }

    short8 bU[3][2];
    short8 bW[3];
#pragma unroll
    for (int g = 0; g < 3; ++g) {
        const int col = g * 64 + u;
#pragma unroll
        for (int ks = 0; ks < 2; ++ks) {
            short8 f;
#pragma unroll
            for (int j = 0; j < 8; ++j) {
                int kp = ks * 32 + q * 8 + j;
                f[j] = (short)U[(size_t)kp * 192 + col];
            }
            bU[g][ks] = f;
        }
        short8 fw;
#pragma unroll
        for (int j = 0; j < 8; ++j) {
            int kp = q * 8 + j;
            fw[j] = (kp < 18) ? (short)W[(size_t)(kp >> 1) * 192 + col] : (short)0;
        }
        bW[g] = fw;
    }

    const float bz  = bf2f(bi[u])       + bf2f(br[u]);
    const float brg = bf2f(bi[64 + u])  + bf2f(br[64 + u]);
    const float bih = bf2f(bi[128 + u]);
    const float brh = bf2f(br[128 + u]);
    const f32x4 Cz  = {bz,  bz,  bz,  bz};
    const f32x4 Cr  = {brg, brg, brg, brg};
    const f32x4 Chx = {bih, bih, bih, bih};
    const f32x4 Chr = {brh, brh, brh, brh};

    float hreg[4];
#pragma unroll
    for (int i = 0; i < 4; ++i) {
        int m = q * 4 + i;
        float hv = bf2f(h0[(size_t)(gb0 + m) * 64 + u]);
        hreg[i] = hv;
        Ah[0][m][u] = f2bf(hv);
    }
    __syncthreads();

    const int r2 = tid >> 3, c2 = tid & 7;
    const int r0x = tid / 9, k0x = tid - 9 * r0x;

    for (int t = 0; t < 72; ++t) {
        const int cur = t & 1, nb = cur ^ 1;

        unsigned short h0v = 0, l0v = 0;
        if (t < 71 && tid < 144) {
            const int tx = dir ? (70 - t) : (t + 1);
            size_t idx = ((size_t)(gb0 + r0x) * 72 + tx) * 9 + k0x;
            if (xbf) { h0v = ((const unsigned short*)X)[idx]; l0v = 0; }
            else { float v = ((const float*)X)[idx]; h0v = f2bf(v); l0v = f2bf(v - bf2f(h0v)); }
        }

        if (t > 0 && tid < 128) {
            const int tw = dir ? (71 - (t - 1)) : (t - 1);
            int4 v = *(const int4*)&Ah[cur][r2][c2 * 8];
            *(int4*)(seq + ((size_t)tw * bchunk + lb0 + r2) * 128 + dir * 64 + c2 * 8) = v;
        }

        const unsigned short* ap = &Ah[cur][ln][0];
        short8 a0 = *(const short8*)(ap + q * 8);
        short8 a1 = *(const short8*)(ap + 32 + q * 8);
        short8 ax = *(const short8*)(&Ax[cur][ln][q * 8]);
        f32x4 az  = MFMA_B16(ax, bW[0], Cz);
        az        = MFMA_B16(a0, bU[0][0], az);
        az        = MFMA_B16(a1, bU[0][1], az);
        f32x4 ar  = MFMA_B16(ax, bW[1], Cr);
        ar        = MFMA_B16(a0, bU[1][0], ar);
        ar        = MFMA_B16(a1, bU[1][1], ar);
        f32x4 ahx = MFMA_B16(ax, bW[2], Chx);
        f32x4 ahr = MFMA_B16(a0, bU[2][0], Chr);
        ahr       = MFMA_B16(a1, bU[2][1], ahr);

#pragma unroll
        for (int i = 0; i < 4; ++i) {
            const int m = q * 4 + i;
            float z = sigm(az[i]);
            float r = sigm(ar[i]);
            float pre = ahx[i] + r * ahr[i];
            float hh = fmaxf(pre, 0.0f);
            float hn = hh + z * (hreg[i] - hh);
            hreg[i] = hn;
            Ah[nb][m][u] = f2bf(hn);
        }

        if (t < 71 && tid < 144) {
            Ax[nb][r0x][2 * k0x]     = h0v;
            Ax[nb][r0x][2 * k0x + 1] = l0v;
        }
        __syncthreads();
    }

    // final flush: h(71) lives in Ah[0]; 16 rows x 8 int4 -> 128 threads
    if (tid < 128) {
        const int tw = dir ? 0 : 71;
        int4 v = *(const int4*)&Ah[0][r2][c2 * 8];
        *(int4*)(seq + ((size_t)tw * bchunk + lb0 + r2) * 128 + dir * 64 + c2 * 8) = v;
    }
}

// ---------------------------------------------------------------------------
// Layer 2: bidirectional GRU(64), tanh. NO As LDS: per-lane seq A-frags direct
// from global one step ahead; 12 projection MFMAs pre-barrier, 6 recurrent
// MFMAs + gates post-barrier. Ah stride 72. grid (bchunk/16, 2), block 256.
// ---------------------------------------------------------------------------
__global__ __launch_bounds__(256, 1)
void gru2_kernel(const unsigned short* __restrict__ seq, int cb, int bchunk,
                 const unsigned short* __restrict__ W2f, const unsigned short* __restrict__ U2f,
                 const unsigned short* __restrict__ bi2f, const unsigned short* __restrict__ br2f,
                 const unsigned short* __restrict__ W2b, const unsigned short* __restrict__ U2b,
                 const unsigned short* __restrict__ bi2b, const unsigned short* __restrict__ br2b,
                 float* __restrict__ feat)
{
    const int tid  = threadIdx.x;
    const int lane = tid & 63;
    const int wv   = tid >> 6;
    const int q    = lane >> 4;
    const int ln   = lane & 15;
    const int dir  = blockIdx.y;
    const int lb0  = blockIdx.x * 16;
    const int gb0  = cb + lb0;
    const int u    = wv * 16 + ln;

    const unsigned short* W  = dir ? W2b  : W2f;
    const unsigned short* U  = dir ? U2b  : U2f;
    const unsigned short* bi = dir ? bi2b : bi2f;
    const unsigned short* br = dir ? br2b : br2f;

    __shared__ __align__(16) unsigned short Ah[2][16][72];

    {
        unsigned short* p = &Ah[0][0][0];
        for (int i = tid; i < 16 * 72; i += 256) p[i] = 0;
    }

    const long long tstride = (long long)bchunk * 128 * (dir ? -1 : 1);
    const unsigned short* sptr0 = seq + ((size_t)(lb0 + ln)) * 128 + q * 8
                                + (dir ? 71ll * bchunk * 128 : 0);

    short8 bU[3][2];
    short8 bV[3][4];
#pragma unroll
    for (int g = 0; g < 3; ++g) {
        const int col = g * 64 + u;
#pragma unroll
        for (int ks = 0; ks < 2; ++ks) {
            short8 f;
#pragma unroll
            for (int j = 0; j < 8; ++j) {
                int kp = ks * 32 + q * 8 + j;
                f[j] = (short)U[(size_t)kp * 192 + col];
            }
            bU[g][ks] = f;
        }
#pragma unroll
        for (int ks = 0; ks < 4; ++ks) {
            short8 fv;
#pragma unroll
            for (int j = 0; j < 8; ++j) {
                int kp = ks * 32 + q * 8 + j;
                fv[j] = (short)W[(size_t)kp * 192 + col];
            }
            bV[g][ks] = fv;
        }
    }

    const float bz  = bf2f(bi[u])       + bf2f(br[u]);
    const float brg = bf2f(bi[64 + u])  + bf2f(br[64 + u]);
    const float bih = bf2f(bi[128 + u]);
    const float brh = bf2f(br[128 + u]);
    const f32x4 Cz  = {bz,  bz,  bz,  bz};
    const f32x4 Cr  = {brg, brg, brg, brg};
    const f32x4 Chx = {bih, bih, bih, bih};
    const f32x4 Chr = {brh, brh, brh, brh};

    float hreg[4];
#pragma unroll
    for (int i = 0; i < 4; ++i) hreg[i] = 0.0f;

    // prologue: load s(0) and compute partials P(0)
    f32x4 P0, P1, P2;
    {
        const unsigned short* sp = sptr0;
        short8 s0 = *(const short8*)(sp);
        short8 s1 = *(const short8*)(sp + 32);
        short8 s2 = *(const short8*)(sp + 64);
        short8 s3 = *(const short8*)(sp + 96);
        P0 = MFMA_B16(s0, bV[0][0], Cz);
        P0 = MFMA_B16(s1, bV[0][1], P0);
        P0 = MFMA_B16(s2, bV[0][2], P0);
        P0 = MFMA_B16(s3, bV[0][3], P0);
        P1 = MFMA_B16(s0, bV[1][0], Cr);
        P1 = MFMA_B16(s1, bV[1][1], P1);
        P1 = MFMA_B16(s2, bV[1][2], P1);
        P1 = MFMA_B16(s3, bV[1][3], P1);
        P2 = MFMA_B16(s0, bV[2][0], Chx);
        P2 = MFMA_B16(s1, bV[2][1], P2);
        P2 = MFMA_B16(s2, bV[2][2], P2);
        P2 = MFMA_B16(s3, bV[2][3], P2);
    }
    __syncthreads();

    for (int t = 0; t < 72; ++t) {
        const int cur = t & 1, nb = cur ^ 1;

        short8 n0, n1, n2, n3;
        const bool pf = (t < 71);
        if (pf) {
            const unsigned short* sp = sptr0 + (long long)(t + 1) * tstride;
            n0 = *(const short8*)(sp);
            n1 = *(const short8*)(sp + 32);
            n2 = *(const short8*)(sp + 64);
            n3 = *(const short8*)(sp + 96);
        }

        const unsigned short* ap = &Ah[cur][ln][0];
        short8 a0 = *(const short8*)(ap + q * 8);
        short8 a1 = *(const short8*)(ap + 32 + q * 8);
        f32x4 az  = MFMA_B16(a0, bU[0][0], P0);
        az        = MFMA_B16(a1, bU[0][1], az);
        f32x4 ar  = MFMA_B16(a0, bU[1][0], P1);
        ar        = MFMA_B16(a1, bU[1][1], ar);
        f32x4 ahr = MFMA_B16(a0, bU[2][0], Chr);
        ahr       = MFMA_B16(a1, bU[2][1], ahr);
        f32x4 ahx = P2;

#pragma unroll
        for (int i = 0; i < 4; ++i) {
            const int m = q * 4 + i;
            float z = sigm(az[i]);
            float r = sigm(ar[i]);
            float pre = ahx[i] + r * ahr[i];
            float hh = tanh_fast(pre);
            float hn = hh + z * (hreg[i] - hh);
            hreg[i] = hn;
            Ah[nb][m][u] = f2bf(hn);
        }

        if (pf) {
            P0 = MFMA_B16(n0, bV[0][0], Cz);
            P0 = MFMA_B16(n1, bV[0][1], P0);
            P0 = MFMA_B16(n2, bV[0][2], P0);
            P0 = MFMA_B16(n3, bV[0][3], P0);
            P1 = MFMA_B16(n0, bV[1][0], Cr);
            P1 = MFMA_B16(n1, bV[1][1], P1);
            P1 = MFMA_B16(n2, bV[1][2], P1);
            P1 = MFMA_B16(n3, bV[1][3], P1);
            P2 = MFMA_B16(n0, bV[2][0], Chx);
            P2 = MFMA_B16(n1, bV[2][1], P2);
            P2 = MFMA_B16(n2, bV[2][2], P2);
            P2 = MFMA_B16(n3, bV[2][3], P2);
        }
        __syncthreads();
    }

#pragma unroll
    for (int i = 0; i < 4; ++i) {
        const int m = q * 4 + i;
        feat[(size_t)(gb0 + m) * 128 + dir * 64 + u] = hreg[i];
    }
}

// ---------------------------------------------------------------------------
__global__ __launch_bounds__(256, 1)
void head_kernel(const float* __restrict__ feat,
                 const unsigned short* __restrict__ dW, const unsigned short* __restrict__ db,
                 const unsigned short* __restrict__ oW, const unsigned short* __restrict__ ob,
                 float* __restrict__ out)
{
    const int tid = threadIdx.x;
    const int b0  = blockIdx.x * 16;

    __shared__ __align__(16) unsigned short Wl[128][136];
    __shared__ __align__(16) float fs[16][128];
    __shared__ __align__(16) float hs[16][136];
    __shared__ __align__(16) float ls[16][32];

    for (int i = tid; i < 2048; i += 256) {
        const int k = i >> 4;
        const int c = (i & 15) * 8;
        *(int4*)&Wl[k][c] = *(const int4*)(dW + (size_t)k * 128 + c);
    }
    {
        const float4* src = (const float4*)(feat + (size_t)b0 * 128);
        float4* dst = (float4*)&fs[0][0];
        for (int i = tid; i < 512; i += 256) dst[i] = src[i];
    }
    __syncthreads();

    {
        const int row = tid >> 4;
        const int j0  = (tid & 15) * 8;
        float acc[8];
#pragma unroll
        for (int jj = 0; jj < 8; ++jj) acc[jj] = bf2f(db[j0 + jj]);
        for (int k = 0; k < 128; ++k) {
            float f = fs[row][k];
            short8 w = *(const short8*)&Wl[k][j0];
#pragma unroll
            for (int jj = 0; jj < 8; ++jj)
                acc[jj] += f * bf2f((unsigned short)w[jj]);
        }
#pragma unroll
        for (int jj = 0; jj < 8; ++jj) hs[row][j0 + jj] = fmaxf(acc[jj], 0.0f);
    }
    __syncthreads();

    for (int e = tid; e < 16 * 24; e += 256) {
        const int row = e / 24, l = e - 24 * row;
        float acc = bf2f(ob[l]);
        for (int k = 0; k < 128; ++k)
            acc += hs[row][k] * bf2f(oW[(size_t)k * 24 + l]);
        ls[row][l] = acc;
    }
    __syncthreads();

    for (int e = tid; e < 16 * 24; e += 256) {
        const int row = e / 24, l = e - 24 * row;
        float mx = ls[row][0];
#pragma unroll
        for (int k = 1; k < 24; ++k) mx = fmaxf(mx, ls[row][k]);
        float s = 0.0f;
#pragma unroll
        for (int k = 0; k < 24; ++k) s += __expf(ls[row][k] - mx);
        float v = __expf(ls[row][l] - mx) * rcp_f(s);
        out[(size_t)(b0 + row) * 24 + l] = v;
    }
}

// ---------------------------------------------------------------------------
extern "C" void kernel_launch(void* const* d_in, const int* in_sizes, int n_in,
                              void* d_out, int out_size, void* d_ws, size_t ws_size,
                              hipStream_t stream) {
    (void)in_sizes; (void)n_in; (void)out_size;

    static const int wc[22] = {
        262144, 262144,
        1728, 12288, 192, 192,
        1728, 12288, 192, 192,
        24576, 12288, 192, 192,
        24576, 12288, 192, 192,
        16384, 128,
        3072, 24
    };

    WArgs a;
    int off = 0;
    for (int t = 0; t < 22; ++t) {
        a.src[t] = d_in[t + 1];
        a.off[t] = off;
        off += wc[t];
    }
    a.off[22] = off;

    const unsigned long long arena_bytes = 1294400ull;
    const unsigned long long feat_bytes  = 4096ull * 128ull * 4ull;
    const unsigned long long seq_full    = 72ull * 4096ull * 128ull * 2ull;
    const unsigned long long fixed       = arena_bytes + feat_bytes;

    int nc = 32;
    for (int c = 1; c <= 32; c *= 2) {
        if (fixed + seq_full / (unsigned long long)c <= (unsigned long long)ws_size) { nc = c; break; }
    }
    const int bchunk = 4096 / nc;

    unsigned short* arena = (unsigned short*)d_ws;
    float* feat           = (float*)((char*)d_ws + arena_bytes);
    unsigned short* seq   = (unsigned short*)((char*)d_ws + fixed);

    convert_w<<<256, 256, 0, stream>>>(a, arena, (const unsigned short*)d_in[0]);

    const unsigned short* h0f  = arena + a.off[0];
    const unsigned short* h0b  = arena + a.off[1];
    const unsigned short* d1fW = arena + a.off[2];
    const unsigned short* d1fU = arena + a.off[3];
    const unsigned short* d1fbi= arena + a.off[4];
    const unsigned short* d1fbr= arena + a.off[5];
    const unsigned short* d1bW = arena + a.off[6];
    const unsigned short* d1bU = arena + a.off[7];
    const unsigned short* d1bbi= arena + a.off[8];
    const unsigned short* d1bbr= arena + a.off[9];
    const unsigned short* d2fW = arena + a.off[10];
    const unsigned short* d2fU = arena + a.off[11];
    const unsigned short* d2fbi= arena + a.off[12];
    const unsigned short* d2fbr= arena + a.off[13];
    const unsigned short* d2bW = arena + a.off[14];
    const unsigned short* d2bU = arena + a.off[15];
    const unsigned short* d2bbi= arena + a.off[16];
    const unsigned short* d2bbr= arena + a.off[17];
    const unsigned short* dW   = arena + a.off[18];
    const unsigned short* db   = arena + a.off[19];
    const unsigned short* oW   = arena + a.off[20];
    const unsigned short* ob   = arena + a.off[21];

    for (int c = 0; c < nc; ++c) {
        const int cb = c * bchunk;
        gru1_kernel<<<dim3(bchunk / 16, 2), 256, 0, stream>>>(
            d_in[0], cb, bchunk,
            h0f, h0b, d1fW, d1fU, d1fbi, d1fbr, d1bW, d1bU, d1bbi, d1bbr, seq);
        gru2_kernel<<<dim3(bchunk / 16, 2), 256, 0, stream>>>(
            seq, cb, bchunk,
            d2fW, d2fU, d2fbi, d2fbr, d2bW, d2bU, d2bbi, d2bbr, feat);
    }
    head_kernel<<<256, 256, 0, stream>>>(
        feat, dW, db, oW, ob, (float*)d_out);
}

// Round 12
// 263.604 us; speedup vs baseline: 1.6557x; 1.0026x over previous
//
#include <hip/hip_runtime.h>
#include <hip/hip_bf16.h>

typedef __attribute__((ext_vector_type(8))) short short8;
typedef __attribute__((ext_vector_type(4))) float f32x4;

#define MFMA_B16(a, b, c) __builtin_amdgcn_mfma_f32_16x16x32_bf16((a), (b), (c), 0, 0, 0)

__device__ __forceinline__ float bf2f(unsigned short u) {
    union { unsigned int i; float f; } v; v.i = ((unsigned int)u) << 16; return v.f;
}
__device__ __forceinline__ unsigned short f2bf(float f) {
    union { float f; unsigned int i; } v; v.f = f;
    unsigned int r = v.i + 0x7fffu + ((v.i >> 16) & 1u);
    return (unsigned short)(r >> 16);
}
// fast HW transcendentals: v_rcp_f32 / v_exp_f32 (1 inst each, ~1 ulp)
__device__ __forceinline__ float rcp_f(float x) { return __builtin_amdgcn_rcpf(x); }
__device__ __forceinline__ float sigm(float x) {
    return rcp_f(1.0f + __builtin_amdgcn_exp2f(-1.44269504f * x));
}
__device__ __forceinline__ float tanh_fast(float x) {
    return 1.0f - 2.0f * rcp_f(__builtin_amdgcn_exp2f(2.88539008f * x) + 1.0f);
}

// probe 256 shorts: bf16 vs fp32 discrimination (deterministic per call)
__device__ __forceinline__ bool probe_bf16(const unsigned short* p, int tid, int* s_cnt) {
    if (tid == 0) *s_cnt = 0;
    __syncthreads();
    unsigned short s = p[tid & 255];
    int e = (s >> 7) & 0xFF;
    if (tid < 256 && e >= 117 && e <= 137) atomicAdd(s_cnt, 1);
    __syncthreads();
    return *s_cnt >= 200;
}

// ---------------------------------------------------------------------------
struct WArgs {
    const void* src[22];
    int off[23];
};

__global__ __launch_bounds__(256)
void convert_w(WArgs a, unsigned short* __restrict__ arena,
               const unsigned short* __restrict__ probe)
{
    __shared__ int cnt;
    const bool bf = probe_bf16(probe, threadIdx.x, &cnt);
    const int total = a.off[22];
    for (int i = blockIdx.x * 256 + threadIdx.x; i < total; i += gridDim.x * 256) {
        int t = 0;
        while (t < 21 && i >= a.off[t + 1]) ++t;
        const int local = i - a.off[t];
        arena[i] = bf ? ((const unsigned short*)a.src[t])[local]
                      : f2bf(((const float*)a.src[t])[local]);
    }
}

// ---------------------------------------------------------------------------
// Layer 1: bidirectional GRU(64), relu candidate. 16 rows/block, h bf16 K=64,
// x hi/lo bf16 K=32 via LDS. Depth-2 x prefetch (load x(t+2), stage x(t+1)).
// grid: (bchunk/16, 2), block 256.
// ---------------------------------------------------------------------------
__global__ __launch_bounds__(256, 1)
void gru1_kernel(const void* __restrict__ X, int cb, int bchunk,
                 const unsigned short* __restrict__ h0f,
                 const unsigned short* __restrict__ h0b,
                 const unsigned short* __restrict__ Wf, const unsigned short* __restrict__ Uf,
                 const unsigned short* __restrict__ bif, const unsigned short* __restrict__ brf,
                 const unsigned short* __restrict__ Wb, const unsigned short* __restrict__ Ub,
                 const unsigned short* __restrict__ bib, const unsigned short* __restrict__ brb,
                 unsigned short* __restrict__ seq)
{
    const int tid  = threadIdx.x;
    const int lane = tid & 63;
    const int wv   = tid >> 6;
    const int q    = lane >> 4;
    const int ln   = lane & 15;
    const int dir  = blockIdx.y;
    const int lb0  = blockIdx.x * 16;
    const int gb0  = cb + lb0;
    const int u    = wv * 16 + ln;

    const unsigned short* W  = dir ? Wb  : Wf;
    const unsigned short* U  = dir ? Ub  : Uf;
    const unsigned short* bi = dir ? bib : bif;
    const unsigned short* br = dir ? brb : brf;
    const unsigned short* h0 = dir ? h0b : h0f;

    __shared__ __align__(16) unsigned short Ah[2][16][72];   // h bf16 (stride 72: 2-way)
    __shared__ __align__(16) unsigned short Ax[2][16][40];   // x hi/lo (18 real), rest 0
    __shared__ int s_cnt;

    const bool xbf = probe_bf16((const unsigned short*)X, tid, &s_cnt);

    {
        unsigned short* p = &Ax[0][0][0];
        for (int i = tid; i < 2 * 16 * 40; i += 256) p[i] = 0;
    }
    __syncthreads();

    {
        const int tx0 = dir ? 71 : 0;
        if (tid < 144) {
            int r = tid / 9, k = tid - 9 * r;
            size_t idx = ((size_t)(gb0 + r) * 72 + tx0) * 9 + k;
            unsigned short hv, lv;
            if (xbf) { hv = ((const unsigned short*)X)[idx]; lv = 0; }
            else { float v = ((const float*)X)[idx]; hv = f2bf(v); lv = f2bf(v - bf2f(hv)); }
            Ax[0][r][2 * k]     = hv;
            Ax[0][r][2 * k + 1] = lv;
        }
    }

    short8 bU[3][2];
    short8 bW[3];
#pragma unroll
    for (int g = 0; g < 3; ++g) {
        const int col = g * 64 + u;
#pragma unroll
        for (int ks = 0; ks < 2; ++ks) {
            short8 f;
#pragma unroll
            for (int j = 0; j < 8; ++j) {
                int kp = ks * 32 + q * 8 + j;
                f[j] = (short)U[(size_t)kp * 192 + col];
            }
            bU[g][ks] = f;
        }
        short8 fw;
#pragma unroll
        for (int j = 0; j < 8; ++j) {
            int kp = q * 8 + j;
            fw[j] = (kp < 18) ? (short)W[(size_t)(kp >> 1) * 192 + col] : (short)0;
        }
        bW[g] = fw;
    }

    const float bz  = bf2f(bi[u])       + bf2f(br[u]);
    const float brg = bf2f(bi[64 + u])  + bf2f(br[64 + u]);
    const float bih = bf2f(bi[128 + u]);
    const float brh = bf2f(br[128 + u]);
    const f32x4 Cz  = {bz,  bz,  bz,  bz};
    const f32x4 Cr  = {brg, brg, brg, brg};
    const f32x4 Chx = {bih, bih, bih, bih};
    const f32x4 Chr = {brh, brh, brh, brh};

    float hreg[4];
#pragma unroll
    for (int i = 0; i < 4; ++i) {
        int m = q * 4 + i;
        float hv = bf2f(h0[(size_t)(gb0 + m) * 64 + u]);
        hreg[i] = hv;
        Ah[0][m][u] = f2bf(hv);
    }

    const int r2 = tid >> 3, c2 = tid & 7;
    const int r0x = tid / 9, k0x = tid - 9 * r0x;

    // depth-2 x pipeline: ch/cl hold x(t+1); preload x(1)
    unsigned short ch = 0, cl = 0;
    if (tid < 144) {
        const int tx = dir ? 70 : 1;
        size_t idx = ((size_t)(gb0 + r0x) * 72 + tx) * 9 + k0x;
        if (xbf) { ch = ((const unsigned short*)X)[idx]; cl = 0; }
        else { float v = ((const float*)X)[idx]; ch = f2bf(v); cl = f2bf(v - bf2f(ch)); }
    }
    __syncthreads();

#pragma unroll 2
    for (int t = 0; t < 72; ++t) {
        const int cur = t & 1, nb = cur ^ 1;

        // issue loads for x(t+2)
        unsigned short fh = 0, fl = 0;
        if (t < 70 && tid < 144) {
            const int tx = dir ? (69 - t) : (t + 2);
            size_t idx = ((size_t)(gb0 + r0x) * 72 + tx) * 9 + k0x;
            if (xbf) { fh = ((const unsigned short*)X)[idx]; fl = 0; }
            else { float v = ((const float*)X)[idx]; fh = f2bf(v); fl = f2bf(v - bf2f(fh)); }
        }

        if (t > 0 && tid < 128) {
            const int tw = dir ? (71 - (t - 1)) : (t - 1);
            int4 v = *(const int4*)&Ah[cur][r2][c2 * 8];
            *(int4*)(seq + ((size_t)tw * bchunk + lb0 + r2) * 128 + dir * 64 + c2 * 8) = v;
        }

        const unsigned short* ap = &Ah[cur][ln][0];
        short8 a0 = *(const short8*)(ap + q * 8);
        short8 a1 = *(const short8*)(ap + 32 + q * 8);
        short8 ax = *(const short8*)(&Ax[cur][ln][q * 8]);
        f32x4 az  = MFMA_B16(ax, bW[0], Cz);
        az        = MFMA_B16(a0, bU[0][0], az);
        az        = MFMA_B16(a1, bU[0][1], az);
        f32x4 ar  = MFMA_B16(ax, bW[1], Cr);
        ar        = MFMA_B16(a0, bU[1][0], ar);
        ar        = MFMA_B16(a1, bU[1][1], ar);
        f32x4 ahx = MFMA_B16(ax, bW[2], Chx);
        f32x4 ahr = MFMA_B16(a0, bU[2][0], Chr);
        ahr       = MFMA_B16(a1, bU[2][1], ahr);

#pragma unroll
        for (int i = 0; i < 4; ++i) {
            const int m = q * 4 + i;
            float z = sigm(az[i]);
            float r = sigm(ar[i]);
            float pre = ahx[i] + r * ahr[i];
            float hh = fmaxf(pre, 0.0f);
            float hn = hh + z * (hreg[i] - hh);
            hreg[i] = hn;
            Ah[nb][m][u] = f2bf(hn);
        }

        // stage x(t+1) (loaded a full step ago) into next LDS buffer
        if (t < 71 && tid < 144) {
            Ax[nb][r0x][2 * k0x]     = ch;
            Ax[nb][r0x][2 * k0x + 1] = cl;
        }
        ch = fh; cl = fl;
        __syncthreads();
    }

    // final flush: h(71) lives in Ah[0]; 16 rows x 8 int4 -> 128 threads
    if (tid < 128) {
        const int tw = dir ? 0 : 71;
        int4 v = *(const int4*)&Ah[0][r2][c2 * 8];
        *(int4*)(seq + ((size_t)tw * bchunk + lb0 + r2) * 128 + dir * 64 + c2 * 8) = v;
    }
}

// ---------------------------------------------------------------------------
// Layer 2: bidirectional GRU(64), tanh. Per-lane seq A-frags direct from
// global with DEPTH-2 prefetch: load s(t+2) at step t, compute P(t+1) from
// regs loaded one step earlier. 12 projection MFMAs pre-barrier, 6 recurrent
// MFMAs + gates post-barrier. grid (bchunk/16, 2), block 256.
// ---------------------------------------------------------------------------
__global__ __launch_bounds__(256, 1)
void gru2_kernel(const unsigned short* __restrict__ seq, int cb, int bchunk,
                 const unsigned short* __restrict__ W2f, const unsigned short* __restrict__ U2f,
                 const unsigned short* __restrict__ bi2f, const unsigned short* __restrict__ br2f,
                 const unsigned short* __restrict__ W2b, const unsigned short* __restrict__ U2b,
                 const unsigned short* __restrict__ bi2b, const unsigned short* __restrict__ br2b,
                 float* __restrict__ feat)
{
    const int tid  = threadIdx.x;
    const int lane = tid & 63;
    const int wv   = tid >> 6;
    const int q    = lane >> 4;
    const int ln   = lane & 15;
    const int dir  = blockIdx.y;
    const int lb0  = blockIdx.x * 16;
    const int gb0  = cb + lb0;
    const int u    = wv * 16 + ln;

    const unsigned short* W  = dir ? W2b  : W2f;
    const unsigned short* U  = dir ? U2b  : U2f;
    const unsigned short* bi = dir ? bi2b : bi2f;
    const unsigned short* br = dir ? br2b : br2f;

    __shared__ __align__(16) unsigned short Ah[2][16][72];

    {
        unsigned short* p = &Ah[0][0][0];
        for (int i = tid; i < 16 * 72; i += 256) p[i] = 0;
    }

    const long long tstride = (long long)bchunk * 128 * (dir ? -1 : 1);
    const unsigned short* sptr0 = seq + ((size_t)(lb0 + ln)) * 128 + q * 8
                                + (dir ? 71ll * bchunk * 128 : 0);

    short8 bU[3][2];
    short8 bV[3][4];
#pragma unroll
    for (int g = 0; g < 3; ++g) {
        const int col = g * 64 + u;
#pragma unroll
        for (int ks = 0; ks < 2; ++ks) {
            short8 f;
#pragma unroll
            for (int j = 0; j < 8; ++j) {
                int kp = ks * 32 + q * 8 + j;
                f[j] = (short)U[(size_t)kp * 192 + col];
            }
            bU[g][ks] = f;
        }
#pragma unroll
        for (int ks = 0; ks < 4; ++ks) {
            short8 fv;
#pragma unroll
            for (int j = 0; j < 8; ++j) {
                int kp = ks * 32 + q * 8 + j;
                fv[j] = (short)W[(size_t)kp * 192 + col];
            }
            bV[g][ks] = fv;
        }
    }

    const float bz  = bf2f(bi[u])       + bf2f(br[u]);
    const float brg = bf2f(bi[64 + u])  + bf2f(br[64 + u]);
    const float bih = bf2f(bi[128 + u]);
    const float brh = bf2f(br[128 + u]);
    const f32x4 Cz  = {bz,  bz,  bz,  bz};
    const f32x4 Cr  = {brg, brg, brg, brg};
    const f32x4 Chx = {bih, bih, bih, bih};
    const f32x4 Chr = {brh, brh, brh, brh};

    float hreg[4];
#pragma unroll
    for (int i = 0; i < 4; ++i) hreg[i] = 0.0f;

    // prologue: P(0) from s(0); preload c = s(1)
    f32x4 P0, P1, P2;
    {
        const unsigned short* sp = sptr0;
        short8 s0 = *(const short8*)(sp);
        short8 s1 = *(const short8*)(sp + 32);
        short8 s2 = *(const short8*)(sp + 64);
        short8 s3 = *(const short8*)(sp + 96);
        P0 = MFMA_B16(s0, bV[0][0], Cz);
        P0 = MFMA_B16(s1, bV[0][1], P0);
        P0 = MFMA_B16(s2, bV[0][2], P0);
        P0 = MFMA_B16(s3, bV[0][3], P0);
        P1 = MFMA_B16(s0, bV[1][0], Cr);
        P1 = MFMA_B16(s1, bV[1][1], P1);
        P1 = MFMA_B16(s2, bV[1][2], P1);
        P1 = MFMA_B16(s3, bV[1][3], P1);
        P2 = MFMA_B16(s0, bV[2][0], Chx);
        P2 = MFMA_B16(s1, bV[2][1], P2);
        P2 = MFMA_B16(s2, bV[2][2], P2);
        P2 = MFMA_B16(s3, bV[2][3], P2);
    }
    short8 c0, c1, c2, c3;   // s(t+1) regs
    {
        const unsigned short* sp = sptr0 + tstride;
        c0 = *(const short8*)(sp);
        c1 = *(const short8*)(sp + 32);
        c2 = *(const short8*)(sp + 64);
        c3 = *(const short8*)(sp + 96);
    }
    __syncthreads();

#pragma unroll 2
    for (int t = 0; t < 72; ++t) {
        const int cur = t & 1, nb = cur ^ 1;

        // issue loads for s(t+2) (consumed in NEXT iteration's P-block)
        short8 f0, f1, f2, f3;
        const bool pf2 = (t < 70);
        if (pf2) {
            const unsigned short* sp = sptr0 + (long long)(t + 2) * tstride;
            f0 = *(const short8*)(sp);
            f1 = *(const short8*)(sp + 32);
            f2 = *(const short8*)(sp + 64);
            f3 = *(const short8*)(sp + 96);
        }

        // post-barrier: finish gates with recurrent terms
        const unsigned short* ap = &Ah[cur][ln][0];
        short8 a0 = *(const short8*)(ap + q * 8);
        short8 a1 = *(const short8*)(ap + 32 + q * 8);
        f32x4 az  = MFMA_B16(a0, bU[0][0], P0);
        az        = MFMA_B16(a1, bU[0][1], az);
        f32x4 ar  = MFMA_B16(a0, bU[1][0], P1);
        ar        = MFMA_B16(a1, bU[1][1], ar);
        f32x4 ahr = MFMA_B16(a0, bU[2][0], Chr);
        ahr       = MFMA_B16(a1, bU[2][1], ahr);
        f32x4 ahx = P2;

#pragma unroll
        for (int i = 0; i < 4; ++i) {
            const int m = q * 4 + i;
            float z = sigm(az[i]);
            float r = sigm(ar[i]);
            float pre = ahx[i] + r * ahr[i];
            float hh = tanh_fast(pre);
            float hn = hh + z * (hreg[i] - hh);
            hreg[i] = hn;
            Ah[nb][m][u] = f2bf(hn);
        }

        // pre-barrier: P(t+1) from c regs (loaded one full step ago)
        if (t < 71) {
            P0 = MFMA_B16(c0, bV[0][0], Cz);
            P0 = MFMA_B16(c1, bV[0][1], P0);
            P0 = MFMA_B16(c2, bV[0][2], P0);
            P0 = MFMA_B16(c3, bV[0][3], P0);
            P1 = MFMA_B16(c0, bV[1][0], Cr);
            P1 = MFMA_B16(c1, bV[1][1], P1);
            P1 = MFMA_B16(c2, bV[1][2], P1);
            P1 = MFMA_B16(c3, bV[1][3], P1);
            P2 = MFMA_B16(c0, bV[2][0], Chx);
            P2 = MFMA_B16(c1, bV[2][1], P2);
            P2 = MFMA_B16(c2, bV[2][2], P2);
            P2 = MFMA_B16(c3, bV[2][3], P2);
        }
        if (pf2) { c0 = f0; c1 = f1; c2 = f2; c3 = f3; }
        __syncthreads();
    }

#pragma unroll
    for (int i = 0; i < 4; ++i) {
        const int m = q * 4 + i;
        feat[(size_t)(gb0 + m) * 128 + dir * 64 + u] = hreg[i];
    }
}

// ---------------------------------------------------------------------------
__global__ __launch_bounds__(256, 1)
void head_kernel(const float* __restrict__ feat,
                 const unsigned short* __restrict__ dW, const unsigned short* __restrict__ db,
                 const unsigned short* __restrict__ oW, const unsigned short* __restrict__ ob,
                 float* __restrict__ out)
{
    const int tid = threadIdx.x;
    const int b0  = blockIdx.x * 16;

    __shared__ __align__(16) unsigned short Wl[128][136];
    __shared__ __align__(16) float fs[16][128];
    __shared__ __align__(16) float hs[16][136];
    __shared__ __align__(16) float ls[16][32];

    for (int i = tid; i < 2048; i += 256) {
        const int k = i >> 4;
        const int c = (i & 15) * 8;
        *(int4*)&Wl[k][c] = *(const int4*)(dW + (size_t)k * 128 + c);
    }
    {
        const float4* src = (const float4*)(feat + (size_t)b0 * 128);
        float4* dst = (float4*)&fs[0][0];
        for (int i = tid; i < 512; i += 256) dst[i] = src[i];
    }
    __syncthreads();

    {
        const int row = tid >> 4;
        const int j0  = (tid & 15) * 8;
        float acc[8];
#pragma unroll
        for (int jj = 0; jj < 8; ++jj) acc[jj] = bf2f(db[j0 + jj]);
        for (int k = 0; k < 128; ++k) {
            float f = fs[row][k];
            short8 w = *(const short8*)&Wl[k][j0];
#pragma unroll
            for (int jj = 0; jj < 8; ++jj)
                acc[jj] += f * bf2f((unsigned short)w[jj]);
        }
#pragma unroll
        for (int jj = 0; jj < 8; ++jj) hs[row][j0 + jj] = fmaxf(acc[jj], 0.0f);
    }
    __syncthreads();

    for (int e = tid; e < 16 * 24; e += 256) {
        const int row = e / 24, l = e - 24 * row;
        float acc = bf2f(ob[l]);
        for (int k = 0; k < 128; ++k)
            acc += hs[row][k] * bf2f(oW[(size_t)k * 24 + l]);
        ls[row][l] = acc;
    }
    __syncthreads();

    for (int e = tid; e < 16 * 24; e += 256) {
        const int row = e / 24, l = e - 24 * row;
        float mx = ls[row][0];
#pragma unroll
        for (int k = 1; k < 24; ++k) mx = fmaxf(mx, ls[row][k]);
        float s = 0.0f;
#pragma unroll
        for (int k = 0; k < 24; ++k) s += __expf(ls[row][k] - mx);
        float v = __expf(ls[row][l] - mx) * rcp_f(s);
        out[(size_t)(b0 + row) * 24 + l] = v;
    }
}

// ---------------------------------------------------------------------------
extern "C" void kernel_launch(void* const* d_in, const int* in_sizes, int n_in,
                              void* d_out, int out_size, void* d_ws, size_t ws_size,
                              hipStream_t stream) {
    (void)in_sizes; (void)n_in; (void)out_size;

    static const int wc[22] = {
        262144, 262144,
        1728, 12288, 192, 192,
        1728, 12288, 192, 192,
        24576, 12288, 192, 192,
        24576, 12288, 192, 192,
        16384, 128,
        3072, 24
    };

    WArgs a;
    int off = 0;
    for (int t = 0; t < 22; ++t) {
        a.src[t] = d_in[t + 1];
        a.off[t] = off;
        off += wc[t];
    }
    a.off[22] = off;

    const unsigned long long arena_bytes = 1294400ull;
    const unsigned long long feat_bytes  = 4096ull * 128ull * 4ull;
    const unsigned long long seq_full    = 72ull * 4096ull * 128ull * 2ull;
    const unsigned long long fixed       = arena_bytes + feat_bytes;

    int nc = 32;
    for (int c = 1; c <= 32; c *= 2) {
        if (fixed + seq_full / (unsigned long long)c <= (unsigned long long)ws_size) { nc = c; break; }
    }
    const int bchunk = 4096 / nc;

    unsigned short* arena = (unsigned short*)d_ws;
    float* feat           = (float*)((char*)d_ws + arena_bytes);
    unsigned short* seq   = (unsigned short*)((char*)d_ws + fixed);

    convert_w<<<256, 256, 0, stream>>>(a, arena, (const unsigned short*)d_in[0]);

    const unsigned short* h0f  = arena + a.off[0];
    const unsigned short* h0b  = arena + a.off[1];
    const unsigned short* d1fW = arena + a.off[2];
    const unsigned short* d1fU = arena + a.off[3];
    const unsigned short* d1fbi= arena + a.off[4];
    const unsigned short* d1fbr= arena + a.off[5];
    const unsigned short* d1bW = arena + a.off[6];
    const unsigned short* d1bU = arena + a.off[7];
    const unsigned short* d1bbi= arena + a.off[8];
    const unsigned short* d1bbr= arena + a.off[9];
    const unsigned short* d2fW = arena + a.off[10];
    const unsigned short* d2fU = arena + a.off[11];
    const unsigned short* d2fbi= arena + a.off[12];
    const unsigned short* d2fbr= arena + a.off[13];
    const unsigned short* d2bW = arena + a.off[14];
    const unsigned short* d2bU = arena + a.off[15];
    const unsigned short* d2bbi= arena + a.off[16];
    const unsigned short* d2bbr= arena + a.off[17];
    const unsigned short* dW   = arena + a.off[18];
    const unsigned short* db   = arena + a.off[19];
    const unsigned short* oW   = arena + a.off[20];
    const unsigned short* ob   = arena + a.off[21];

    for (int c = 0; c < nc; ++c) {
        const int cb = c * bchunk;
        gru1_kernel<<<dim3(bchunk / 16, 2), 256, 0, stream>>>(
            d_in[0], cb, bchunk,
            h0f, h0b, d1fW, d1fU, d1fbi, d1fbr, d1bW, d1bU, d1bbi, d1bbr, seq);
        gru2_kernel<<<dim3(bchunk / 16, 2), 256, 0, stream>>>(
            seq, cb, bchunk,
            d2fW, d2fU, d2fbi, d2fbr, d2bW, d2bU, d2bbi, d2bbr, feat);
    }
    head_kernel<<<256, 256, 0, stream>>>(
        feat, dW, db, oW, ob, (float*)d_out);
}

// Round 13
// 254.192 us; speedup vs baseline: 1.7170x; 1.0370x over previous
//
#include <hip/hip_runtime.h>
#include <hip/hip_bf16.h>

typedef __attribute__((ext_vector_type(8))) short short8;
typedef __attribute__((ext_vector_type(4))) float f32x4;

#define MFMA_B16(a, b, c) __builtin_amdgcn_mfma_f32_16x16x32_bf16((a), (b), (c), 0, 0, 0)

__device__ __forceinline__ float bf2f(unsigned short u) {
    union { unsigned int i; float f; } v; v.i = ((unsigned int)u) << 16; return v.f;
}
__device__ __forceinline__ unsigned short f2bf(float f) {
    union { float f; unsigned int i; } v; v.f = f;
    unsigned int r = v.i + 0x7fffu + ((v.i >> 16) & 1u);
    return (unsigned short)(r >> 16);
}
// fast HW transcendentals (1 inst each). Gate scale constants are folded into
// the weights at convert time: z/r pre-acts arrive pre-multiplied by -log2(e),
// gru2 candidate pre-acts by 2*log2(e).
__device__ __forceinline__ float rcp_f(float x) { return __builtin_amdgcn_rcpf(x); }
__device__ __forceinline__ float sigm_pre(float x) {      // x = -log2(e)*(...)
    return rcp_f(1.0f + __builtin_amdgcn_exp2f(x));
}
__device__ __forceinline__ float tanh_pre(float x) {      // x = 2*log2(e)*(...)
    return 1.0f - 2.0f * rcp_f(__builtin_amdgcn_exp2f(x) + 1.0f);
}

// probe 256 shorts: bf16 vs fp32 discrimination (deterministic per call)
__device__ __forceinline__ bool probe_bf16(const unsigned short* p, int tid, int* s_cnt) {
    if (tid == 0) *s_cnt = 0;
    __syncthreads();
    unsigned short s = p[tid & 255];
    int e = (s >> 7) & 0xFF;
    if (tid < 256 && e >= 117 && e <= 137) atomicAdd(s_cnt, 1);
    __syncthreads();
    return *s_cnt >= 200;
}

// ---------------------------------------------------------------------------
// Convert 20 weight/bias tensors (NOT x, NOT h0) to a bf16 arena with gate
// scale folding. Tensors 0..15 are GRU (last dim 192): cols 0..127 (z,r gates)
// scaled by -log2(e); cols 128..191 scaled by 2*log2(e) for d2 (tanh) tensors
// (8..15), by 1 for d1 (relu) tensors (0..7). Tensors 16..19 (head) unscaled.
// ---------------------------------------------------------------------------
struct WArgs {
    const void* src[20];
    int off[21];
};

__global__ __launch_bounds__(256)
void convert_w(WArgs a, unsigned short* __restrict__ arena,
               const unsigned short* __restrict__ probe)
{
    __shared__ int cnt;
    const bool bf = probe_bf16(probe, threadIdx.x, &cnt);
    const int total = a.off[20];
    for (int i = blockIdx.x * 256 + threadIdx.x; i < total; i += gridDim.x * 256) {
        int t = 0;
        while (t < 19 && i >= a.off[t + 1]) ++t;
        const int local = i - a.off[t];
        float v = bf ? bf2f(((const unsigned short*)a.src[t])[local])
                     : ((const float*)a.src[t])[local];
        if (t < 16) {
            const int col = local % 192;
            if (col < 128) v *= -1.4426950408889634f;
            else if (t >= 8) v *= 2.885390081777927f;
        }
        arena[i] = f2bf(v);
    }
}

// ---------------------------------------------------------------------------
// Layer 1: bidirectional GRU(64), relu candidate. 16 rows/block, h bf16 K=64,
// x hi/lo bf16 K=32 via LDS, depth-2 x prefetch. h0 converted inline.
// grid: (bchunk/16, 2), block 256.
// ---------------------------------------------------------------------------
__global__ __launch_bounds__(256, 1)
void gru1_kernel(const void* __restrict__ X, const void* __restrict__ h0f,
                 const void* __restrict__ h0b, int cb, int bchunk,
                 const unsigned short* __restrict__ Wf, const unsigned short* __restrict__ Uf,
                 const unsigned short* __restrict__ bif, const unsigned short* __restrict__ brf,
                 const unsigned short* __restrict__ Wb, const unsigned short* __restrict__ Ub,
                 const unsigned short* __restrict__ bib, const unsigned short* __restrict__ brb,
                 unsigned short* __restrict__ seq)
{
    const int tid  = threadIdx.x;
    const int lane = tid & 63;
    const int wv   = tid >> 6;
    const int q    = lane >> 4;
    const int ln   = lane & 15;
    const int dir  = blockIdx.y;
    const int lb0  = blockIdx.x * 16;
    const int gb0  = cb + lb0;
    const int u    = wv * 16 + ln;

    const unsigned short* W  = dir ? Wb  : Wf;
    const unsigned short* U  = dir ? Ub  : Uf;
    const unsigned short* bi = dir ? bib : bif;
    const unsigned short* br = dir ? brb : brf;
    const void* h0 = dir ? h0b : h0f;

    __shared__ __align__(16) unsigned short Ah[2][16][72];
    __shared__ __align__(16) unsigned short Ax[2][16][40];
    __shared__ int s_cnt;

    const bool xbf = probe_bf16((const unsigned short*)X, tid, &s_cnt);

    {
        unsigned short* p = &Ax[0][0][0];
        for (int i = tid; i < 2 * 16 * 40; i += 256) p[i] = 0;
    }
    __syncthreads();

    {
        const int tx0 = dir ? 71 : 0;
        if (tid < 144) {
            int r = tid / 9, k = tid - 9 * r;
            size_t idx = ((size_t)(gb0 + r) * 72 + tx0) * 9 + k;
            unsigned short hv, lv;
            if (xbf) { hv = ((const unsigned short*)X)[idx]; lv = 0; }
            else { float v = ((const float*)X)[idx]; hv = f2bf(v); lv = f2bf(v - bf2f(hv)); }
            Ax[0][r][2 * k]     = hv;
            Ax[0][r][2 * k + 1] = lv;
        }
    }

    short8 bU[3][2];
    short8 bW[3];
#pragma unroll
    for (int g = 0; g < 3; ++g) {
        const int col = g * 64 + u;
#pragma unroll
        for (int ks = 0; ks < 2; ++ks) {
            short8 f;
#pragma unroll
            for (int j = 0; j < 8; ++j) {
                int kp = ks * 32 + q * 8 + j;
                f[j] = (short)U[(size_t)kp * 192 + col];
            }
            bU[g][ks] = f;
        }
        short8 fw;
#pragma unroll
        for (int j = 0; j < 8; ++j) {
            int kp = q * 8 + j;
            fw[j] = (kp < 18) ? (short)W[(size_t)(kp >> 1) * 192 + col] : (short)0;
        }
        bW[g] = fw;
    }

    const float bz  = bf2f(bi[u])       + bf2f(br[u]);        // pre-scaled
    const float brg = bf2f(bi[64 + u])  + bf2f(br[64 + u]);   // pre-scaled
    const float bih = bf2f(bi[128 + u]);                      // unscaled (relu)
    const float brh = bf2f(br[128 + u]);
    const f32x4 Cz  = {bz,  bz,  bz,  bz};
    const f32x4 Cr  = {brg, brg, brg, brg};
    const f32x4 Chx = {bih, bih, bih, bih};
    const f32x4 Chr = {brh, brh, brh, brh};

    float hreg[4];
#pragma unroll
    for (int i = 0; i < 4; ++i) {
        int m = q * 4 + i;
        size_t idx = (size_t)(gb0 + m) * 64 + u;
        float hv = xbf ? bf2f(((const unsigned short*)h0)[idx])
                       : ((const float*)h0)[idx];
        hreg[i] = hv;
        Ah[0][m][u] = f2bf(hv);
    }

    const int r2 = tid >> 3, c2 = tid & 7;
    const int r0x = tid / 9, k0x = tid - 9 * r0x;

    // depth-2 x pipeline: ch/cl hold x(t+1); preload x(1)
    unsigned short ch = 0, cl = 0;
    if (tid < 144) {
        const int tx = dir ? 70 : 1;
        size_t idx = ((size_t)(gb0 + r0x) * 72 + tx) * 9 + k0x;
        if (xbf) { ch = ((const unsigned short*)X)[idx]; cl = 0; }
        else { float v = ((const float*)X)[idx]; ch = f2bf(v); cl = f2bf(v - bf2f(ch)); }
    }
    __syncthreads();

#pragma unroll 2
    for (int t = 0; t < 72; ++t) {
        const int cur = t & 1, nb = cur ^ 1;

        unsigned short fh = 0, fl = 0;
        if (t < 70 && tid < 144) {
            const int tx = dir ? (69 - t) : (t + 2);
            size_t idx = ((size_t)(gb0 + r0x) * 72 + tx) * 9 + k0x;
            if (xbf) { fh = ((const unsigned short*)X)[idx]; fl = 0; }
            else { float v = ((const float*)X)[idx]; fh = f2bf(v); fl = f2bf(v - bf2f(fh)); }
        }

        if (t > 0 && tid < 128) {
            const int tw = dir ? (71 - (t - 1)) : (t - 1);
            int4 v = *(const int4*)&Ah[cur][r2][c2 * 8];
            *(int4*)(seq + ((size_t)tw * bchunk + lb0 + r2) * 128 + dir * 64 + c2 * 8) = v;
        }

        const unsigned short* ap = &Ah[cur][ln][0];
        short8 a0 = *(const short8*)(ap + q * 8);
        short8 a1 = *(const short8*)(ap + 32 + q * 8);
        short8 ax = *(const short8*)(&Ax[cur][ln][q * 8]);
        f32x4 az  = MFMA_B16(ax, bW[0], Cz);
        az        = MFMA_B16(a0, bU[0][0], az);
        az        = MFMA_B16(a1, bU[0][1], az);
        f32x4 ar  = MFMA_B16(ax, bW[1], Cr);
        ar        = MFMA_B16(a0, bU[1][0], ar);
        ar        = MFMA_B16(a1, bU[1][1], ar);
        f32x4 ahx = MFMA_B16(ax, bW[2], Chx);
        f32x4 ahr = MFMA_B16(a0, bU[2][0], Chr);
        ahr       = MFMA_B16(a1, bU[2][1], ahr);

#pragma unroll
        for (int i = 0; i < 4; ++i) {
            const int m = q * 4 + i;
            float z = sigm_pre(az[i]);
            float r = sigm_pre(ar[i]);
            float pre = ahx[i] + r * ahr[i];
            float hh = fmaxf(pre, 0.0f);
            float hn = hh + z * (hreg[i] - hh);
            hreg[i] = hn;
            Ah[nb][m][u] = f2bf(hn);
        }

        if (t < 71 && tid < 144) {
            Ax[nb][r0x][2 * k0x]     = ch;
            Ax[nb][r0x][2 * k0x + 1] = cl;
        }
        ch = fh; cl = fl;
        __syncthreads();
    }

    if (tid < 128) {
        const int tw = dir ? 0 : 71;
        int4 v = *(const int4*)&Ah[0][r2][c2 * 8];
        *(int4*)(seq + ((size_t)tw * bchunk + lb0 + r2) * 128 + dir * 64 + c2 * 8) = v;
    }
}

// ---------------------------------------------------------------------------
// Layer 2: bidirectional GRU(64), tanh (pre-scaled candidate). Per-lane seq
// A-frags direct from global, depth-2 prefetch; 12 projection MFMAs
// pre-barrier, 6 recurrent + gates post-barrier. grid (bchunk/16, 2).
// ---------------------------------------------------------------------------
__global__ __launch_bounds__(256, 1)
void gru2_kernel(const unsigned short* __restrict__ seq, int cb, int bchunk,
                 const unsigned short* __restrict__ W2f, const unsigned short* __restrict__ U2f,
                 const unsigned short* __restrict__ bi2f, const unsigned short* __restrict__ br2f,
                 const unsigned short* __restrict__ W2b, const unsigned short* __restrict__ U2b,
                 const unsigned short* __restrict__ bi2b, const unsigned short* __restrict__ br2b,
                 float* __restrict__ feat)
{
    const int tid  = threadIdx.x;
    const int lane = tid & 63;
    const int wv   = tid >> 6;
    const int q    = lane >> 4;
    const int ln   = lane & 15;
    const int dir  = blockIdx.y;
    const int lb0  = blockIdx.x * 16;
    const int gb0  = cb + lb0;
    const int u    = wv * 16 + ln;

    const unsigned short* W  = dir ? W2b  : W2f;
    const unsigned short* U  = dir ? U2b  : U2f;
    const unsigned short* bi = dir ? bi2b : bi2f;
    const unsigned short* br = dir ? br2b : br2f;

    __shared__ __align__(16) unsigned short Ah[2][16][72];

    {
        unsigned short* p = &Ah[0][0][0];
        for (int i = tid; i < 16 * 72; i += 256) p[i] = 0;
    }

    const long long tstride = (long long)bchunk * 128 * (dir ? -1 : 1);
    const unsigned short* sptr0 = seq + ((size_t)(lb0 + ln)) * 128 + q * 8
                                + (dir ? 71ll * bchunk * 128 : 0);

    short8 bU[3][2];
    short8 bV[3][4];
#pragma unroll
    for (int g = 0; g < 3; ++g) {
        const int col = g * 64 + u;
#pragma unroll
        for (int ks = 0; ks < 2; ++ks) {
            short8 f;
#pragma unroll
            for (int j = 0; j < 8; ++j) {
                int kp = ks * 32 + q * 8 + j;
                f[j] = (short)U[(size_t)kp * 192 + col];
            }
            bU[g][ks] = f;
        }
#pragma unroll
        for (int ks = 0; ks < 4; ++ks) {
            short8 fv;
#pragma unroll
            for (int j = 0; j < 8; ++j) {
                int kp = ks * 32 + q * 8 + j;
                fv[j] = (short)W[(size_t)kp * 192 + col];
            }
            bV[g][ks] = fv;
        }
    }

    const float bz  = bf2f(bi[u])       + bf2f(br[u]);        // pre-scaled
    const float brg = bf2f(bi[64 + u])  + bf2f(br[64 + u]);   // pre-scaled
    const float bih = bf2f(bi[128 + u]);                      // pre-scaled (tanh)
    const float brh = bf2f(br[128 + u]);
    const f32x4 Cz  = {bz,  bz,  bz,  bz};
    const f32x4 Cr  = {brg, brg, brg, brg};
    const f32x4 Chx = {bih, bih, bih, bih};
    const f32x4 Chr = {brh, brh, brh, brh};

    float hreg[4];
#pragma unroll
    for (int i = 0; i < 4; ++i) hreg[i] = 0.0f;

    f32x4 P0, P1, P2;
    {
        const unsigned short* sp = sptr0;
        short8 s0 = *(const short8*)(sp);
        short8 s1 = *(const short8*)(sp + 32);
        short8 s2 = *(const short8*)(sp + 64);
        short8 s3 = *(const short8*)(sp + 96);
        P0 = MFMA_B16(s0, bV[0][0], Cz);
        P0 = MFMA_B16(s1, bV[0][1], P0);
        P0 = MFMA_B16(s2, bV[0][2], P0);
        P0 = MFMA_B16(s3, bV[0][3], P0);
        P1 = MFMA_B16(s0, bV[1][0], Cr);
        P1 = MFMA_B16(s1, bV[1][1], P1);
        P1 = MFMA_B16(s2, bV[1][2], P1);
        P1 = MFMA_B16(s3, bV[1][3], P1);
        P2 = MFMA_B16(s0, bV[2][0], Chx);
        P2 = MFMA_B16(s1, bV[2][1], P2);
        P2 = MFMA_B16(s2, bV[2][2], P2);
        P2 = MFMA_B16(s3, bV[2][3], P2);
    }
    short8 c0, c1, c2, c3;
    {
        const unsigned short* sp = sptr0 + tstride;
        c0 = *(const short8*)(sp);
        c1 = *(const short8*)(sp + 32);
        c2 = *(const short8*)(sp + 64);
        c3 = *(const short8*)(sp + 96);
    }
    __syncthreads();

#pragma unroll 2
    for (int t = 0; t < 72; ++t) {
        const int cur = t & 1, nb = cur ^ 1;

        short8 f0, f1, f2, f3;
        const bool pf2 = (t < 70);
        if (pf2) {
            const unsigned short* sp = sptr0 + (long long)(t + 2) * tstride;
            f0 = *(const short8*)(sp);
            f1 = *(const short8*)(sp + 32);
            f2 = *(const short8*)(sp + 64);
            f3 = *(const short8*)(sp + 96);
        }

        const unsigned short* ap = &Ah[cur][ln][0];
        short8 a0 = *(const short8*)(ap + q * 8);
        short8 a1 = *(const short8*)(ap + 32 + q * 8);
        f32x4 az  = MFMA_B16(a0, bU[0][0], P0);
        az        = MFMA_B16(a1, bU[0][1], az);
        f32x4 ar  = MFMA_B16(a0, bU[1][0], P1);
        ar        = MFMA_B16(a1, bU[1][1], ar);
        f32x4 ahr = MFMA_B16(a0, bU[2][0], Chr);
        ahr       = MFMA_B16(a1, bU[2][1], ahr);
        f32x4 ahx = P2;

#pragma unroll
        for (int i = 0; i < 4; ++i) {
            const int m = q * 4 + i;
            float z = sigm_pre(az[i]);
            float r = sigm_pre(ar[i]);
            float pre = ahx[i] + r * ahr[i];
            float hh = tanh_pre(pre);
            float hn = hh + z * (hreg[i] - hh);
            hreg[i] = hn;
            Ah[nb][m][u] = f2bf(hn);
        }

        if (t < 71) {
            P0 = MFMA_B16(c0, bV[0][0], Cz);
            P0 = MFMA_B16(c1, bV[0][1], P0);
            P0 = MFMA_B16(c2, bV[0][2], P0);
            P0 = MFMA_B16(c3, bV[0][3], P0);
            P1 = MFMA_B16(c0, bV[1][0], Cr);
            P1 = MFMA_B16(c1, bV[1][1], P1);
            P1 = MFMA_B16(c2, bV[1][2], P1);
            P1 = MFMA_B16(c3, bV[1][3], P1);
            P2 = MFMA_B16(c0, bV[2][0], Chx);
            P2 = MFMA_B16(c1, bV[2][1], P2);
            P2 = MFMA_B16(c2, bV[2][2], P2);
            P2 = MFMA_B16(c3, bV[2][3], P2);
        }
        if (pf2) { c0 = f0; c1 = f1; c2 = f2; c3 = f3; }
        __syncthreads();
    }

#pragma unroll
    for (int i = 0; i < 4; ++i) {
        const int m = q * 4 + i;
        feat[(size_t)(gb0 + m) * 128 + dir * 64 + u] = hreg[i];
    }
}

// ---------------------------------------------------------------------------
__global__ __launch_bounds__(256, 1)
void head_kernel(const float* __restrict__ feat,
                 const unsigned short* __restrict__ dW, const unsigned short* __restrict__ db,
                 const unsigned short* __restrict__ oW, const unsigned short* __restrict__ ob,
                 float* __restrict__ out)
{
    const int tid = threadIdx.x;
    const int b0  = blockIdx.x * 16;

    __shared__ __align__(16) unsigned short Wl[128][136];
    __shared__ __align__(16) float fs[16][128];
    __shared__ __align__(16) float hs[16][136];
    __shared__ __align__(16) float ls[16][32];

    for (int i = tid; i < 2048; i += 256) {
        const int k = i >> 4;
        const int c = (i & 15) * 8;
        *(int4*)&Wl[k][c] = *(const int4*)(dW + (size_t)k * 128 + c);
    }
    {
        const float4* src = (const float4*)(feat + (size_t)b0 * 128);
        float4* dst = (float4*)&fs[0][0];
        for (int i = tid; i < 512; i += 256) dst[i] = src[i];
    }
    __syncthreads();

    {
        const int row = tid >> 4;
        const int j0  = (tid & 15) * 8;
        float acc[8];
#pragma unroll
        for (int jj = 0; jj < 8; ++jj) acc[jj] = bf2f(db[j0 + jj]);
        for (int k = 0; k < 128; ++k) {
            float f = fs[row][k];
            short8 w = *(const short8*)&Wl[k][j0];
#pragma unroll
            for (int jj = 0; jj < 8; ++jj)
                acc[jj] += f * bf2f((unsigned short)w[jj]);
        }
#pragma unroll
        for (int jj = 0; jj < 8; ++jj) hs[row][j0 + jj] = fmaxf(acc[jj], 0.0f);
    }
    __syncthreads();

    for (int e = tid; e < 16 * 24; e += 256) {
        const int row = e / 24, l = e - 24 * row;
        float acc = bf2f(ob[l]);
        for (int k = 0; k < 128; ++k)
            acc += hs[row][k] * bf2f(oW[(size_t)k * 24 + l]);
        ls[row][l] = acc;
    }
    __syncthreads();

    for (int e = tid; e < 16 * 24; e += 256) {
        const int row = e / 24, l = e - 24 * row;
        float mx = ls[row][0];
#pragma unroll
        for (int k = 1; k < 24; ++k) mx = fmaxf(mx, ls[row][k]);
        float s = 0.0f;
#pragma unroll
        for (int k = 0; k < 24; ++k) s += __expf(ls[row][k] - mx);
        float v = __expf(ls[row][l] - mx) * rcp_f(s);
        out[(size_t)(b0 + row) * 24 + l] = v;
    }
}

// ---------------------------------------------------------------------------
extern "C" void kernel_launch(void* const* d_in, const int* in_sizes, int n_in,
                              void* d_out, int out_size, void* d_ws, size_t ws_size,
                              hipStream_t stream) {
    (void)in_sizes; (void)n_in; (void)out_size;

    // arena tensors: d_in[3..18] (GRU weights/biases), d_in[19..22] (head)
    static const int wc[20] = {
        1728, 12288, 192, 192,     // d1f W,U,bi,br   (t 0..3)
        1728, 12288, 192, 192,     // d1b             (t 4..7)
        24576, 12288, 192, 192,    // d2f             (t 8..11)
        24576, 12288, 192, 192,    // d2b             (t 12..15)
        16384, 128,                // dense           (t 16,17)
        3072, 24                   // out             (t 18,19)
    };

    WArgs a;
    int off = 0;
    for (int t = 0; t < 20; ++t) {
        a.src[t] = d_in[t + 3];
        a.off[t] = off;
        off += wc[t];
    }
    a.off[20] = off;                         // 122,904 elements

    const unsigned long long arena_bytes = 245952ull;  // 122,904*2 padded to 16
    const unsigned long long feat_bytes  = 4096ull * 128ull * 4ull;
    const unsigned long long seq_full    = 72ull * 4096ull * 128ull * 2ull;
    const unsigned long long fixed       = arena_bytes + feat_bytes;

    int nc = 32;
    for (int c = 1; c <= 32; c *= 2) {
        if (fixed + seq_full / (unsigned long long)c <= (unsigned long long)ws_size) { nc = c; break; }
    }
    const int bchunk = 4096 / nc;

    unsigned short* arena = (unsigned short*)d_ws;
    float* feat           = (float*)((char*)d_ws + arena_bytes);
    unsigned short* seq   = (unsigned short*)((char*)d_ws + fixed);

    convert_w<<<128, 256, 0, stream>>>(a, arena, (const unsigned short*)d_in[0]);

    const unsigned short* d1fW = arena + a.off[0];
    const unsigned short* d1fU = arena + a.off[1];
    const unsigned short* d1fbi= arena + a.off[2];
    const unsigned short* d1fbr= arena + a.off[3];
    const unsigned short* d1bW = arena + a.off[4];
    const unsigned short* d1bU = arena + a.off[5];
    const unsigned short* d1bbi= arena + a.off[6];
    const unsigned short* d1bbr= arena + a.off[7];
    const unsigned short* d2fW = arena + a.off[8];
    const unsigned short* d2fU = arena + a.off[9];
    const unsigned short* d2fbi= arena + a.off[10];
    const unsigned short* d2fbr= arena + a.off[11];
    const unsigned short* d2bW = arena + a.off[12];
    const unsigned short* d2bU = arena + a.off[13];
    const unsigned short* d2bbi= arena + a.off[14];
    const unsigned short* d2bbr= arena + a.off[15];
    const unsigned short* dW   = arena + a.off[16];
    const unsigned short* db   = arena + a.off[17];
    const unsigned short* oW   = arena + a.off[18];
    const unsigned short* ob   = arena + a.off[19];

    for (int c = 0; c < nc; ++c) {
        const int cb = c * bchunk;
        gru1_kernel<<<dim3(bchunk / 16, 2), 256, 0, stream>>>(
            d_in[0], d_in[1], d_in[2], cb, bchunk,
            d1fW, d1fU, d1fbi, d1fbr, d1bW, d1bU, d1bbi, d1bbr, seq);
        gru2_kernel<<<dim3(bchunk / 16, 2), 256, 0, stream>>>(
            seq, cb, bchunk,
            d2fW, d2fU, d2fbi, d2fbr, d2bW, d2bU, d2bbi, d2bbr, feat);
    }
    head_kernel<<<256, 256, 0, stream>>>(
        feat, dW, db, oW, ob, (float*)d_out);
}